// Round 2
// baseline (564.803 us; speedup 1.0000x reference)
//
#include <hip/hip_runtime.h>

#define SEQ 4096
#define CDN 0.35355339059327379f   // 64^(-1/4)
#define DIAGC 0.0625f              // 0.5 * CDN^2
#define KEPS 1e-4f

typedef _Float16 f16;
typedef f16 f16x8 __attribute__((ext_vector_type(8)));
typedef f16 f16x4 __attribute__((ext_vector_type(4)));
typedef float f32x4 __attribute__((ext_vector_type(4)));

#define MFMA16(a, b, c) __builtin_amdgcn_mfma_f32_16x16x32_f16(a, b, c, 0, 0, 0)

// proj fragment direct from f32 (L2-resident 64 KB), converted once at hoist time:
// rows m = 16*mt + (lane&15), d = ks*32 + (lane>>4)*8 .. +7
__device__ __forceinline__ f16x8 pfrag32(const float* __restrict__ proj, int mt, int ks, int lane) {
  const float4* p = (const float4*)(proj + (size_t)(16 * mt + (lane & 15)) * 64 + ks * 32 + (lane >> 4) * 8);
  float4 a = p[0], b = p[1];
  f16x8 r = {(f16)a.x, (f16)a.y, (f16)a.z, (f16)a.w,
             (f16)b.x, (f16)b.y, (f16)b.z, (f16)b.w};
  return r;
}

// q/k row fragment scaled by CDN; accumulates raw sum-of-squares into sq
__device__ __forceinline__ f16x8 row_frag(const float* __restrict__ base, int lane, int ks, float& sq) {
  const float4* p = (const float4*)(base + (size_t)(lane & 15) * 64 + ks * 32 + (lane >> 4) * 8);
  float4 a = p[0], b = p[1];
  sq += a.x*a.x + a.y*a.y + a.z*a.z + a.w*a.w + b.x*b.x + b.y*b.y + b.z*b.z + b.w*b.w;
  f16x8 r = {(f16)(a.x*CDN), (f16)(a.y*CDN), (f16)(a.z*CDN), (f16)(a.w*CDN),
             (f16)(b.x*CDN), (f16)(b.y*CDN), (f16)(b.z*CDN), (f16)(b.w*CDN)};
  return r;
}

__device__ __forceinline__ f16x8 row_frag_ns(const float* __restrict__ base, int lane, int ks) {
  const float4* p = (const float4*)(base + (size_t)(lane & 15) * 64 + ks * 32 + (lane >> 4) * 8);
  float4 a = p[0], b = p[1];
  f16x8 r = {(f16)(a.x*CDN), (f16)(a.y*CDN), (f16)(a.z*CDN), (f16)(a.w*CDN),
             (f16)(b.x*CDN), (f16)(b.y*CDN), (f16)(b.z*CDN), (f16)(b.w*CDN)};
  return r;
}

// ---------------- K1: per-bh global max of dd_k -> 8 partials per bh ----------------
// proj fragments hoisted into 128 VGPRs (loop-invariant): zero LDS in the K-loop.
__global__ __launch_bounds__(256, 2) void k1_stab(
    const float* __restrict__ kk, const float* __restrict__ proj,
    float* __restrict__ ws_stab) {
  __shared__ float wred[4];
  int bh = blockIdx.x >> 3, blk = blockIdx.x & 7;
  int w = threadIdx.x >> 6, lane = threadIdx.x & 63;
  f16x8 pf[16][2];
#pragma unroll
  for (int mt = 0; mt < 16; ++mt) {
    pf[mt][0] = pfrag32(proj, mt, 0, lane);
    pf[mt][1] = pfrag32(proj, mt, 1, lane);
  }
  const float* kbh = kk + (size_t)bh * SEQ * 64;
  float rmax = -1e30f;
#pragma unroll 1
  for (int it = 0; it < 8; ++it) {
    int n0 = blk * 512 + it * 64 + w * 16;
    f16x8 b0 = row_frag_ns(kbh + (size_t)n0 * 64, lane, 0);
    f16x8 b1 = row_frag_ns(kbh + (size_t)n0 * 64, lane, 1);
#pragma unroll
    for (int mt = 0; mt < 16; ++mt) {
      f32x4 acc = {0.f, 0.f, 0.f, 0.f};
      acc = MFMA16(pf[mt][0], b0, acc);
      acc = MFMA16(pf[mt][1], b1, acc);
      rmax = fmaxf(rmax, fmaxf(fmaxf(acc[0], acc[1]), fmaxf(acc[2], acc[3])));
    }
  }
#pragma unroll
  for (int m = 1; m < 64; m <<= 1) rmax = fmaxf(rmax, __shfl_xor(rmax, m, 64));
  if (lane == 0) wred[w] = rmax;
  __syncthreads();
  if (threadIdx.x == 0)
    ws_stab[bh * 8 + blk] = fmaxf(fmaxf(wred[0], wred[1]), fmaxf(wred[2], wred[3]));
}

// ---------------- K2: m-split, full-n register accumulation. NO partials, NO K2b. --
// grid = mc-major (mc*64 + bh) so the 4 blocks sharing a bh map to the same XCD
// (idx % 8 == bh % 8) -> k/v re-reads are L2-served.
// 512 threads = 8 waves: wave w -> m-tile (w&3), n-half (w>>2).
// Each wave accumulates its complete 16m x 64e ctx tile over all 4096 rows.
#define VSTR 72

__device__ __forceinline__ void stage_v64(const float* __restrict__ vrow, f16* dst, int vr, int ec) {
  const float4* vp = (const float4*)(vrow + ec);
  float4 a = vp[0], b = vp[1];
  dst[(ec + 0) * VSTR + vr] = (f16)a.x;
  dst[(ec + 1) * VSTR + vr] = (f16)a.y;
  dst[(ec + 2) * VSTR + vr] = (f16)a.z;
  dst[(ec + 3) * VSTR + vr] = (f16)a.w;
  dst[(ec + 4) * VSTR + vr] = (f16)b.x;
  dst[(ec + 5) * VSTR + vr] = (f16)b.y;
  dst[(ec + 6) * VSTR + vr] = (f16)b.z;
  dst[(ec + 7) * VSTR + vr] = (f16)b.w;
}

__global__ __launch_bounds__(512, 2) void k2_ctx(
    const float* __restrict__ kk, const float* __restrict__ vv,
    const float* __restrict__ proj, const float* __restrict__ ws_stab,
    float* __restrict__ ws_kcum, f16* __restrict__ ws_ctxT) {
  __shared__ __align__(16) f16 vt[2][64 * VSTR];   // v^T [e][n64], double-buffered
  __shared__ __align__(16) f16 pht[8][16 * 40];    // per-wave phi^T [m16][n32]
  __shared__ __align__(16) float diag_s[8][32];
  __shared__ float red2[4][16];
  int bh = blockIdx.x & 63, mc = blockIdx.x >> 6;
  int w = threadIdx.x >> 6, lane = threadIdx.x & 63;
  int q4 = lane >> 4, l15 = lane & 15;
  int mtl = w & 3, nsub = w >> 2;
  int mbase = mc * 64 + mtl * 16;
  float stab = -1e30f;
#pragma unroll
  for (int i = 0; i < 8; ++i) stab = fmaxf(stab, ws_stab[bh * 8 + i]);
  // this wave's 2 proj fragments (loop-invariant, 8 VGPRs)
  f16x8 pa0 = pfrag32(proj, mc * 4 + mtl, 0, lane);
  f16x8 pa1 = pfrag32(proj, mc * 4 + mtl, 1, lane);
  const float* kbh = kk + (size_t)bh * SEQ * 64;
  const float* vbh = vv + (size_t)bh * SEQ * 64;
  f32x4 actx[4];
  f32x4 akc = {0.f, 0.f, 0.f, 0.f};
#pragma unroll
  for (int i = 0; i < 4; ++i) actx[i] = (f32x4){0.f, 0.f, 0.f, 0.f};
  f16x8 ones = {(f16)1.f, (f16)1.f, (f16)1.f, (f16)1.f,
                (f16)1.f, (f16)1.f, (f16)1.f, (f16)1.f};
  int vr = threadIdx.x >> 3, ec = (threadIdx.x & 7) * 8;
  stage_v64(vbh + (size_t)vr * 64, &vt[0][0], vr, ec);
  __syncthreads();
#pragma unroll 1
  for (int it = 0; it < 64; ++it) {
    int n0 = it * 64;
    if (it < 63) stage_v64(vbh + (size_t)(n0 + 64 + vr) * 64, &vt[(it & 1) ^ 1][0], vr, ec);
    const f16* vcur = &vt[it & 1][0];
    // k row frags (A-operand) + per-row diag for this wave's 32 rows
    f16x8 ak[2][2];
    float dg[2];
#pragma unroll
    for (int nt = 0; nt < 2; ++nt) {
      float sq = 0.f;
      const float* kb = kbh + (size_t)(n0 + nsub * 32 + nt * 16) * 64;
      ak[nt][0] = row_frag(kb, lane, 0, sq);
      ak[nt][1] = row_frag(kb, lane, 1, sq);
      sq += __shfl_xor(sq, 16, 64);
      sq += __shfl_xor(sq, 32, 64);
      dg[nt] = sq * DIAGC;
    }
    if (lane < 16) { diag_s[w][lane] = dg[0]; diag_s[w][16 + lane] = dg[1]; }
    // dd (C: row n = q4*4+reg, col m = l15) -> phi -> pht[w] (same-wave, lockstep)
#pragma unroll
    for (int nt = 0; nt < 2; ++nt) {
      f32x4 acc = {0.f, 0.f, 0.f, 0.f};
      acc = MFMA16(ak[nt][0], pa0, acc);
      acc = MFMA16(ak[nt][1], pa1, acc);
      float4 dgv = ((const float4*)&diag_s[w][0])[nt * 4 + q4];
      f16x4 ph;
      ph[0] = (f16)(__expf(acc[0] - dgv.x - stab) + KEPS);
      ph[1] = (f16)(__expf(acc[1] - dgv.y - stab) + KEPS);
      ph[2] = (f16)(__expf(acc[2] - dgv.z - stab) + KEPS);
      ph[3] = (f16)(__expf(acc[3] - dgv.w - stab) + KEPS);
      *(f16x4*)(&pht[w][l15 * 40 + nt * 16 + q4 * 4]) = ph;
    }
    // vt[it&1] made valid by previous iteration's barrier
    f16x8 bv[4];
#pragma unroll
    for (int et = 0; et < 4; ++et)
      bv[et] = *(const f16x8*)(vcur + (l15 + 16 * et) * VSTR + nsub * 32 + q4 * 8);
    f16x8 aph = *(const f16x8*)(&pht[w][l15 * 40 + q4 * 8]);
    akc = MFMA16(aph, ones, akc);
#pragma unroll
    for (int et = 0; et < 4; ++et) actx[et] = MFMA16(aph, bv[et], actx[et]);
    __syncthreads();  // next-window vt ready; protects vt overwrite next iter
  }
  // cross n-half reduction (reuse vt LDS), then direct f16 ctxT + fp32 kcum write
  float* red = (float*)&vt[0][0];  // 16 KB needed, 18 KB available
  if (nsub == 1) {
#pragma unroll
    for (int et = 0; et < 4; ++et)
#pragma unroll
      for (int r = 0; r < 4; ++r)
        red[mtl * 1024 + (q4 * 4 + r) * 64 + l15 + 16 * et] = actx[et][r];
    if (l15 == 0) {
#pragma unroll
      for (int r = 0; r < 4; ++r) red2[mtl][q4 * 4 + r] = akc[r];
    }
  }
  __syncthreads();
  if (nsub == 0) {
    f16* ct = ws_ctxT + (size_t)bh * 16384;
#pragma unroll
    for (int et = 0; et < 4; ++et) {
      f16x4 h;
#pragma unroll
      for (int r = 0; r < 4; ++r)
        h[r] = (f16)(actx[et][r] + red[mtl * 1024 + (q4 * 4 + r) * 64 + l15 + 16 * et]);
      *(f16x4*)(ct + (size_t)(l15 + 16 * et) * 256 + mbase + q4 * 4) = h;
    }
    if (l15 == 0) {
#pragma unroll
      for (int r = 0; r < 4; ++r)
        ws_kcum[bh * 256 + mbase + q4 * 4 + r] = akc[r] + red2[mtl][q4 * 4 + r];
    }
  }
}

// ---------------- K3: dd_q -> phi_q -> out = (phi_q @ ctx) / (phi_q . kcum) ----------
// proj fragments register-hoisted (128 VGPRs); ctxT staged once into LDS
// (stride 264 f16 -> uniform bank tiling for the b128 fragment reads).
#define CSTR 264

__global__ __launch_bounds__(256, 2) void k3_out(
    const float* __restrict__ qq, const float* __restrict__ proj,
    const float* __restrict__ ws_kcum, const f16* __restrict__ ws_ctxT,
    float* __restrict__ out) {
  __shared__ __align__(16) f16 ctx_l[64 * CSTR];
  __shared__ __align__(16) f16 pht[4][16 * 264];  // per-wave phi^T2 [n16][m256]
  __shared__ __align__(16) float kcl[256];
  int bh = blockIdx.x >> 4, blk = blockIdx.x & 15;
  int t = threadIdx.x;
  kcl[t] = ws_kcum[bh * 256 + t];
  {
    const f16* cb = ws_ctxT + (size_t)bh * 16384;
#pragma unroll
    for (int i = 0; i < 8; ++i) {
      int c = t + i * 256;
      int e = c >> 5, mo = (c & 31) * 8;
      *(f16x8*)(ctx_l + e * CSTR + mo) = *(const f16x8*)(cb + e * 256 + mo);
    }
  }
  int w = t >> 6, lane = t & 63;
  int q4 = lane >> 4, l15 = lane & 15;
  f16x8 pf[16][2];
#pragma unroll
  for (int mt = 0; mt < 16; ++mt) {
    pf[mt][0] = pfrag32(proj, mt, 0, lane);
    pf[mt][1] = pfrag32(proj, mt, 1, lane);
  }
  const float* qbh = qq + (size_t)bh * SEQ * 64;
  float* obh = out + (size_t)bh * SEQ * 64;
  __syncthreads();
#pragma unroll 1
  for (int it = 0; it < 4; ++it) {
    int n0 = blk * 256 + w * 64 + it * 16;
    float sq = 0.f;
    f16x8 bq0 = row_frag(qbh + (size_t)n0 * 64, lane, 0, sq);
    f16x8 bq1 = row_frag(qbh + (size_t)n0 * 64, lane, 1, sq);
    sq += __shfl_xor(sq, 16, 64);
    sq += __shfl_xor(sq, 32, 64);
    float diag = sq * DIAGC;  // diag for column n = n0 + l15 (ddT orientation)
    f32x4 dd[16];
#pragma unroll
    for (int mt = 0; mt < 16; ++mt) {
      f32x4 acc = {0.f, 0.f, 0.f, 0.f};
      acc = MFMA16(pf[mt][0], bq0, acc);
      acc = MFMA16(pf[mt][1], bq1, acc);
      dd[mt] = acc;  // ddT: row m = 16*mt + 4*q4 + reg, col n = l15
    }
    float st = -1e30f;
#pragma unroll
    for (int mt = 0; mt < 16; ++mt)
      st = fmaxf(st, fmaxf(fmaxf(dd[mt][0], dd[mt][1]), fmaxf(dd[mt][2], dd[mt][3])));
    st = fmaxf(st, __shfl_xor(st, 16, 64));
    st = fmaxf(st, __shfl_xor(st, 32, 64));  // per-q-row max
    float dacc = 0.f;
#pragma unroll
    for (int mt = 0; mt < 16; ++mt) {
      float4 kc = ((const float4*)kcl)[mt * 4 + q4];
      float e0 = __expf(dd[mt][0] - diag - st) + KEPS;
      float e1 = __expf(dd[mt][1] - diag - st) + KEPS;
      float e2 = __expf(dd[mt][2] - diag - st) + KEPS;
      float e3 = __expf(dd[mt][3] - diag - st) + KEPS;
      dacc += e0 * kc.x + e1 * kc.y + e2 * kc.z + e3 * kc.w;
      f16x4 ph;
      ph[0] = (f16)e0; ph[1] = (f16)e1; ph[2] = (f16)e2; ph[3] = (f16)e3;
      *(f16x4*)(&pht[w][l15 * 264 + mt * 16 + q4 * 4]) = ph;
    }
    dacc += __shfl_xor(dacc, 16, 64);
    dacc += __shfl_xor(dacc, 32, 64);
    float dinv = 1.0f / dacc;
    f32x4 ao[4];
#pragma unroll
    for (int r = 0; r < 4; ++r) ao[r] = (f32x4){0.f, 0.f, 0.f, 0.f};
#pragma unroll
    for (int ks2 = 0; ks2 < 8; ++ks2) {
      f16x8 bph = *(const f16x8*)(&pht[w][l15 * 264 + ks2 * 32 + q4 * 8]);
#pragma unroll
      for (int rte = 0; rte < 4; ++rte) {
        f16x8 act = *(const f16x8*)(ctx_l + (l15 + 16 * rte) * CSTR + ks2 * 32 + q4 * 8);
        ao[rte] = MFMA16(act, bph, ao[rte]);  // outT: row e, col n
      }
    }
#pragma unroll
    for (int rte = 0; rte < 4; ++rte) {
      float4 o;
      o.x = ao[rte][0] * dinv;
      o.y = ao[rte][1] * dinv;
      o.z = ao[rte][2] * dinv;
      o.w = ao[rte][3] * dinv;
      *(float4*)(obh + (size_t)(n0 + l15) * 64 + rte * 16 + q4 * 4) = o;
    }
  }
}

extern "C" void kernel_launch(void* const* d_in, const int* in_sizes, int n_in,
                              void* d_out, int out_size, void* d_ws, size_t ws_size,
                              hipStream_t stream) {
  const float* q = (const float*)d_in[0];
  const float* k = (const float*)d_in[1];
  const float* v = (const float*)d_in[2];
  const float* proj = (const float*)d_in[3];
  float* out = (float*)d_out;
  float* ws = (float*)d_ws;
  // ws layout (floats): stab 1024 | kcum 16384 | ctxT f16[64][64][256] (524288 f)
  // => 2.17 MB total, byte-identical footprint to the proven 485us session.
  // d_out is not used as scratch: K1/K2 never touch it, K3 writes it exactly once.
  float* ws_stab = ws;                         // 512 used (1024 reserved)
  float* ws_kcum = ws + 1024;                  // 16384 floats
  f16*   ws_ctxT = (f16*)(ws + 17408);         // 1,048,576 f16
  k1_stab<<<512, 256, 0, stream>>>(k, proj, ws_stab);
  k2_ctx<<<256, 512, 0, stream>>>(k, v, proj, ws_stab, ws_kcum, ws_ctxT);
  k3_out<<<1024, 256, 0, stream>>>(q, proj, ws_kcum, ws_ctxT, out);
}

// Round 3
// 478.237 us; speedup vs baseline: 1.1810x; 1.1810x over previous
//
#include <hip/hip_runtime.h>

#define SEQ 4096
#define CDN 0.35355339059327379f   // 64^(-1/4)
#define DIAGC 0.0625f              // 0.5 * CDN^2
#define KEPS 1e-4f

typedef _Float16 f16;
typedef f16 f16x8 __attribute__((ext_vector_type(8)));
typedef f16 f16x4 __attribute__((ext_vector_type(4)));
typedef float f32x4 __attribute__((ext_vector_type(4)));

#define MFMA16(a, b, c) __builtin_amdgcn_mfma_f32_16x16x32_f16(a, b, c, 0, 0, 0)

// ---- proj staged to LDS: 256 rows x stride 72 f16 (b128 reads, conflict-spread) --
#define PSTR 72

__device__ __forceinline__ void stage_proj(const float* __restrict__ proj, f16* plds) {
  int t = threadIdx.x;
  int mrow = t >> 2;
  int cb = (t & 3) * 16;
#pragma unroll
  for (int p = 0; p < 4; ++p) {
    int m = mrow + p * 64;
    const float4* src = (const float4*)(proj + m * 64 + cb);
    f16* dst = plds + m * PSTR + cb;
#pragma unroll
    for (int i = 0; i < 4; ++i) {
      float4 v = src[i];
      f16x4 h = {(f16)v.x, (f16)v.y, (f16)v.z, (f16)v.w};
      *(f16x4*)(dst + i * 4) = h;
    }
  }
}

__device__ __forceinline__ f16x8 proj_frag(const f16* plds, int mtile, int ks, int lane) {
  int m = (lane & 15) + 16 * mtile;
  return *(const f16x8*)(plds + m * PSTR + ks * 32 + (lane >> 4) * 8);
}

// proj fragment direct from f32 global (used where only 2 frags/wave are needed)
__device__ __forceinline__ f16x8 pfrag32(const float* __restrict__ proj, int mt, int ks, int lane) {
  const float4* p = (const float4*)(proj + (size_t)(16 * mt + (lane & 15)) * 64 + ks * 32 + (lane >> 4) * 8);
  float4 a = p[0], b = p[1];
  f16x8 r = {(f16)a.x, (f16)a.y, (f16)a.z, (f16)a.w,
             (f16)b.x, (f16)b.y, (f16)b.z, (f16)b.w};
  return r;
}

// q/k row fragment scaled by CDN; accumulates raw sum-of-squares into sq
__device__ __forceinline__ f16x8 row_frag(const float* __restrict__ base, int lane, int ks, float& sq) {
  const float4* p = (const float4*)(base + (size_t)(lane & 15) * 64 + ks * 32 + (lane >> 4) * 8);
  float4 a = p[0], b = p[1];
  sq += a.x*a.x + a.y*a.y + a.z*a.z + a.w*a.w + b.x*b.x + b.y*b.y + b.z*b.z + b.w*b.w;
  f16x8 r = {(f16)(a.x*CDN), (f16)(a.y*CDN), (f16)(a.z*CDN), (f16)(a.w*CDN),
             (f16)(b.x*CDN), (f16)(b.y*CDN), (f16)(b.z*CDN), (f16)(b.w*CDN)};
  return r;
}

__device__ __forceinline__ f16x8 row_frag_ns(const float* __restrict__ base, int lane, int ks) {
  const float4* p = (const float4*)(base + (size_t)(lane & 15) * 64 + ks * 32 + (lane >> 4) * 8);
  float4 a = p[0], b = p[1];
  f16x8 r = {(f16)(a.x*CDN), (f16)(a.y*CDN), (f16)(a.z*CDN), (f16)(a.w*CDN),
             (f16)(b.x*CDN), (f16)(b.y*CDN), (f16)(b.z*CDN), (f16)(b.w*CDN)};
  return r;
}

// ---------------- K1: per-bh global max of dd_k -> 8 partials per bh ----------------
__global__ __launch_bounds__(256, 2) void k1_stab(
    const float* __restrict__ kk, const float* __restrict__ proj,
    float* __restrict__ ws_stab) {
  __shared__ float wred[4];
  int bh = blockIdx.x >> 3, blk = blockIdx.x & 7;
  int w = threadIdx.x >> 6, lane = threadIdx.x & 63;
  f16x8 pf[16][2];
#pragma unroll
  for (int mt = 0; mt < 16; ++mt) {
    pf[mt][0] = pfrag32(proj, mt, 0, lane);
    pf[mt][1] = pfrag32(proj, mt, 1, lane);
  }
  const float* kbh = kk + (size_t)bh * SEQ * 64;
  float rmax = -1e30f;
#pragma unroll 1
  for (int it = 0; it < 8; ++it) {
    int n0 = blk * 512 + it * 64 + w * 16;
    f16x8 b0 = row_frag_ns(kbh + (size_t)n0 * 64, lane, 0);
    f16x8 b1 = row_frag_ns(kbh + (size_t)n0 * 64, lane, 1);
#pragma unroll
    for (int mt = 0; mt < 16; ++mt) {
      f32x4 acc = {0.f, 0.f, 0.f, 0.f};
      acc = MFMA16(pf[mt][0], b0, acc);
      acc = MFMA16(pf[mt][1], b1, acc);
      rmax = fmaxf(rmax, fmaxf(fmaxf(acc[0], acc[1]), fmaxf(acc[2], acc[3])));
    }
  }
#pragma unroll
  for (int m = 1; m < 64; m <<= 1) rmax = fmaxf(rmax, __shfl_xor(rmax, m, 64));
  if (lane == 0) wred[w] = rmax;
  __syncthreads();
  if (threadIdx.x == 0)
    ws_stab[bh * 8 + blk] = fmaxf(fmaxf(wred[0], wred[1]), fmaxf(wred[2], wred[3]));
}

// ---------------- K2: m-split x ns-split, register ctx accumulation ----------------
// grid = (ns*4 + mc)*64 + bh  (bh-minor => 8 blocks of a bh share one XCD's L2).
// 512 blocks = 2 blocks/CU x 8 waves = 16 waves/CU. Each block: 2048 rows, 32 iters.
// 8 waves: wave w -> m-tile (w&3), n-half (w>>2).
#define VSTR 72

// v-transpose staging, lane-major over n: store banks = nl/2 -> all 32 banks (2-way
// pairs are free) -> kills the 16-way conflict of the vr=tid>>3 mapping.
__device__ __forceinline__ void stage_vT(const float* __restrict__ vbh, int n, int e8, int nl, f16* dst) {
  const float4* vp = (const float4*)(vbh + (size_t)n * 64 + e8);
  float4 a = vp[0], b = vp[1];
  dst[(e8 + 0) * VSTR + nl] = (f16)a.x;
  dst[(e8 + 1) * VSTR + nl] = (f16)a.y;
  dst[(e8 + 2) * VSTR + nl] = (f16)a.z;
  dst[(e8 + 3) * VSTR + nl] = (f16)a.w;
  dst[(e8 + 4) * VSTR + nl] = (f16)b.x;
  dst[(e8 + 5) * VSTR + nl] = (f16)b.y;
  dst[(e8 + 6) * VSTR + nl] = (f16)b.z;
  dst[(e8 + 7) * VSTR + nl] = (f16)b.w;
}

__global__ __launch_bounds__(512, 4) void k2_ctx(
    const float* __restrict__ kk, const float* __restrict__ vv,
    const float* __restrict__ proj, const float* __restrict__ ws_stab,
    float* __restrict__ ctx_part, float* __restrict__ kcum_part) {
  __shared__ __align__(16) f16 vt[2][64 * VSTR];   // v^T [e][n64], double-buffered
  __shared__ __align__(16) f16 pht[8][16 * 40];    // per-wave phi^T [m16][n32]
  __shared__ __align__(16) float diag_s[8][32];
  __shared__ float red2[4][16];
  int bh = blockIdx.x & 63, rest = blockIdx.x >> 6;
  int mc = rest & 3, ns = rest >> 2;
  int w = threadIdx.x >> 6, lane = threadIdx.x & 63;
  int q4 = lane >> 4, l15 = lane & 15;
  int mtl = w & 3, nsub = w >> 2;
  float stab = -1e30f;
#pragma unroll
  for (int i = 0; i < 8; ++i) stab = fmaxf(stab, ws_stab[bh * 8 + i]);
  f16x8 pa0 = pfrag32(proj, mc * 4 + mtl, 0, lane);
  f16x8 pa1 = pfrag32(proj, mc * 4 + mtl, 1, lane);
  const float* kbh = kk + (size_t)bh * SEQ * 64;
  const float* vbh = vv + (size_t)bh * SEQ * 64;
  f32x4 actx[4];
  f32x4 akc = {0.f, 0.f, 0.f, 0.f};
#pragma unroll
  for (int i = 0; i < 4; ++i) actx[i] = (f32x4){0.f, 0.f, 0.f, 0.f};
  f16x8 ones = {(f16)1.f, (f16)1.f, (f16)1.f, (f16)1.f,
                (f16)1.f, (f16)1.f, (f16)1.f, (f16)1.f};
  int nl = threadIdx.x & 63, e8 = (threadIdx.x >> 6) * 8;
  int nbase = ns * 2048;
  stage_vT(vbh, nbase + nl, e8, nl, &vt[0][0]);
  __syncthreads();
#pragma unroll 1
  for (int it = 0; it < 32; ++it) {
    int n0 = nbase + it * 64;
    if (it < 31) stage_vT(vbh, n0 + 64 + nl, e8, nl, &vt[(it & 1) ^ 1][0]);
    const f16* vcur = &vt[it & 1][0];
    // k row frags (A-operand) + per-row diag for this wave's 32 rows
    f16x8 ak[2][2];
    float dg[2];
#pragma unroll
    for (int nt = 0; nt < 2; ++nt) {
      float sq = 0.f;
      const float* kb = kbh + (size_t)(n0 + nsub * 32 + nt * 16) * 64;
      ak[nt][0] = row_frag(kb, lane, 0, sq);
      ak[nt][1] = row_frag(kb, lane, 1, sq);
      sq += __shfl_xor(sq, 16, 64);
      sq += __shfl_xor(sq, 32, 64);
      dg[nt] = sq * DIAGC;
    }
    if (lane < 16) { diag_s[w][lane] = dg[0]; diag_s[w][16 + lane] = dg[1]; }
    // dd (C: row n = q4*4+reg, col m = l15) -> phi -> pht[w] (same-wave, lockstep)
#pragma unroll
    for (int nt = 0; nt < 2; ++nt) {
      f32x4 acc = {0.f, 0.f, 0.f, 0.f};
      acc = MFMA16(ak[nt][0], pa0, acc);
      acc = MFMA16(ak[nt][1], pa1, acc);
      float4 dgv = ((const float4*)&diag_s[w][0])[nt * 4 + q4];
      f16x4 ph;
      ph[0] = (f16)(__expf(acc[0] - dgv.x - stab) + KEPS);
      ph[1] = (f16)(__expf(acc[1] - dgv.y - stab) + KEPS);
      ph[2] = (f16)(__expf(acc[2] - dgv.z - stab) + KEPS);
      ph[3] = (f16)(__expf(acc[3] - dgv.w - stab) + KEPS);
      *(f16x4*)(&pht[w][l15 * 40 + nt * 16 + q4 * 4]) = ph;
    }
    f16x8 bv[4];
#pragma unroll
    for (int et = 0; et < 4; ++et)
      bv[et] = *(const f16x8*)(vcur + (l15 + 16 * et) * VSTR + nsub * 32 + q4 * 8);
    f16x8 aph = *(const f16x8*)(&pht[w][l15 * 40 + q4 * 8]);
    akc = MFMA16(aph, ones, akc);
#pragma unroll
    for (int et = 0; et < 4; ++et) actx[et] = MFMA16(aph, bv[et], actx[et]);
    __syncthreads();  // next vt buffer ready; protects vt before next overwrite
  }
  // cross n-half reduction (reuse vt LDS), then f32 partial stores (L2-resident)
  float* red = (float*)&vt[0][0];  // 16 KB needed, 18 KB available in vt[0]
  if (nsub == 1) {
#pragma unroll
    for (int et = 0; et < 4; ++et)
#pragma unroll
      for (int r = 0; r < 4; ++r)
        red[mtl * 1024 + (q4 * 4 + r) * 64 + l15 + 16 * et] = actx[et][r];
    if (l15 == 0) {
#pragma unroll
      for (int r = 0; r < 4; ++r) red2[mtl][q4 * 4 + r] = akc[r];
    }
  }
  __syncthreads();
  if (nsub == 0) {
    float* cp = ctx_part + (((size_t)bh * 2 + ns) * 256 + mc * 64 + mtl * 16) * 64;
#pragma unroll
    for (int et = 0; et < 4; ++et)
#pragma unroll
      for (int r = 0; r < 4; ++r)
        cp[(size_t)(q4 * 4 + r) * 64 + l15 + 16 * et] =
            actx[et][r] + red[mtl * 1024 + (q4 * 4 + r) * 64 + l15 + 16 * et];
    if (l15 == 0) {
#pragma unroll
      for (int r = 0; r < 4; ++r)
        kcum_part[((size_t)bh * 2 + ns) * 256 + mc * 64 + mtl * 16 + q4 * 4 + r] =
            akc[r] + red2[mtl][q4 * 4 + r];
    }
  }
}

// ---------------- K2c: sum 2 ns-partials -> fp32 kcum + f16 ctxT [e][m] ------------
// grid = mq*64 + bh (bh-minor => same XCD as producers => partials are L2 hits).
__global__ __launch_bounds__(256) void k2c_red(
    const float* __restrict__ ctx_part, const float* __restrict__ kcum_part,
    float* __restrict__ ws_kcum, f16* __restrict__ ws_ctxT) {
  __shared__ float tile[64 * 65];
  int bh = blockIdx.x & 63, mq = blockIdx.x >> 6;
  int t = threadIdx.x;
  const float* c0 = ctx_part + (((size_t)bh * 2 + 0) * 256 + mq * 64) * 64;
  const float* c1 = ctx_part + (((size_t)bh * 2 + 1) * 256 + mq * 64) * 64;
#pragma unroll
  for (int i = 0; i < 16; ++i) {
    int idx = t + i * 256;
    int ml = idx >> 6, e = idx & 63;
    tile[ml * 65 + e] = c0[idx] + c1[idx];
  }
  if (t < 64) {
    ws_kcum[bh * 256 + mq * 64 + t] =
        kcum_part[((size_t)bh * 2 + 0) * 256 + mq * 64 + t] +
        kcum_part[((size_t)bh * 2 + 1) * 256 + mq * 64 + t];
  }
  __syncthreads();
  f16* ct = ws_ctxT + (size_t)bh * 16384 + mq * 64;
  int mj = t & 63, eg = t >> 6;
#pragma unroll
  for (int i = 0; i < 16; ++i) {
    int e = eg + i * 4;
    ct[(size_t)e * 256 + mj] = (f16)tile[mj * 65 + e];
  }
}

// ---------------- K3: dd_q -> phi_q -> out = (phi_q @ ctx) / (phi_q . kcum) --------
// proj via LDS (plds, proven); ctxT staged once into LDS; phi processed in m-quarters
// through a small per-wave phq buffer. LDS total 79,872 B -> 2 blocks/CU.
#define CSTR 264

__global__ __launch_bounds__(256, 2) void k3_out(
    const float* __restrict__ qq, const float* __restrict__ proj,
    const float* __restrict__ ws_kcum, const f16* __restrict__ ws_ctxT,
    float* __restrict__ out) {
  __shared__ __align__(16) f16 plds[256 * PSTR];   // 36864 B
  __shared__ __align__(16) f16 ctx_l[64 * CSTR];   // 33792 B
  __shared__ __align__(16) f16 phq[4][16 * 72];    // 9216 B, per-wave quarter buffer
  int bh = blockIdx.x >> 4, blk = blockIdx.x & 15;
  int t = threadIdx.x;
  stage_proj(proj, plds);
  {
    const f16* cb = ws_ctxT + (size_t)bh * 16384;
#pragma unroll
    for (int i = 0; i < 8; ++i) {
      int c = t + i * 256;
      int e = c >> 5, mo = (c & 31) * 8;
      *(f16x8*)(ctx_l + e * CSTR + mo) = *(const f16x8*)(cb + e * 256 + mo);
    }
  }
  int w = t >> 6, lane = t & 63;
  int q4 = lane >> 4, l15 = lane & 15;
  const float* qbh = qq + (size_t)bh * SEQ * 64;
  const float4* kcv = (const float4*)(ws_kcum + bh * 256);  // 1 KB, L1-hot
  float* obh = out + (size_t)bh * SEQ * 64;
  __syncthreads();
#pragma unroll 1
  for (int it = 0; it < 4; ++it) {
    int n0 = blk * 256 + w * 64 + it * 16;
    float sq = 0.f;
    f16x8 bq0 = row_frag(qbh + (size_t)n0 * 64, lane, 0, sq);
    f16x8 bq1 = row_frag(qbh + (size_t)n0 * 64, lane, 1, sq);
    sq += __shfl_xor(sq, 16, 64);
    sq += __shfl_xor(sq, 32, 64);
    float diag = sq * DIAGC;  // diag for column n = n0 + l15 (ddT orientation)
    f32x4 dd[16];
#pragma unroll
    for (int mt = 0; mt < 16; ++mt) {
      f32x4 acc = {0.f, 0.f, 0.f, 0.f};
      acc = MFMA16(proj_frag(plds, mt, 0, lane), bq0, acc);
      acc = MFMA16(proj_frag(plds, mt, 1, lane), bq1, acc);
      dd[mt] = acc;  // ddT: row m = 16*mt + 4*q4 + reg, col n = l15
    }
    float st = -1e30f;
#pragma unroll
    for (int mt = 0; mt < 16; ++mt)
      st = fmaxf(st, fmaxf(fmaxf(dd[mt][0], dd[mt][1]), fmaxf(dd[mt][2], dd[mt][3])));
    st = fmaxf(st, __shfl_xor(st, 16, 64));
    st = fmaxf(st, __shfl_xor(st, 32, 64));  // per-q-row max
    float dacc = 0.f;
    f32x4 ao[4];
#pragma unroll
    for (int r = 0; r < 4; ++r) ao[r] = (f32x4){0.f, 0.f, 0.f, 0.f};
#pragma unroll
    for (int qtr = 0; qtr < 4; ++qtr) {
#pragma unroll
      for (int m2 = 0; m2 < 4; ++m2) {
        int mt = qtr * 4 + m2;
        float4 kc = kcv[mt * 4 + q4];
        float e0 = __expf(dd[mt][0] - diag - st) + KEPS;
        float e1 = __expf(dd[mt][1] - diag - st) + KEPS;
        float e2 = __expf(dd[mt][2] - diag - st) + KEPS;
        float e3 = __expf(dd[mt][3] - diag - st) + KEPS;
        dacc += e0 * kc.x + e1 * kc.y + e2 * kc.z + e3 * kc.w;
        f16x4 ph;
        ph[0] = (f16)e0; ph[1] = (f16)e1; ph[2] = (f16)e2; ph[3] = (f16)e3;
        *(f16x4*)(&phq[w][l15 * 72 + m2 * 16 + q4 * 4]) = ph;
      }
      // wave-local write->read (lockstep, compiler inserts lgkmcnt)
#pragma unroll
      for (int kl = 0; kl < 2; ++kl) {
        int ks2 = qtr * 2 + kl;
        f16x8 bph = *(const f16x8*)(&phq[w][l15 * 72 + kl * 32 + q4 * 8]);
#pragma unroll
        for (int rte = 0; rte < 4; ++rte) {
          f16x8 act = *(const f16x8*)(ctx_l + (l15 + 16 * rte) * CSTR + ks2 * 32 + q4 * 8);
          ao[rte] = MFMA16(act, bph, ao[rte]);  // outT: row e, col n
        }
      }
    }
    dacc += __shfl_xor(dacc, 16, 64);
    dacc += __shfl_xor(dacc, 32, 64);
    float dinv = 1.0f / dacc;
#pragma unroll
    for (int rte = 0; rte < 4; ++rte) {
      float4 o;
      o.x = ao[rte][0] * dinv;
      o.y = ao[rte][1] * dinv;
      o.z = ao[rte][2] * dinv;
      o.w = ao[rte][3] * dinv;
      *(float4*)(obh + (size_t)(n0 + l15) * 64 + rte * 16 + q4 * 4) = o;
    }
  }
}

extern "C" void kernel_launch(void* const* d_in, const int* in_sizes, int n_in,
                              void* d_out, int out_size, void* d_ws, size_t ws_size,
                              hipStream_t stream) {
  const float* q = (const float*)d_in[0];
  const float* k = (const float*)d_in[1];
  const float* v = (const float*)d_in[2];
  const float* proj = (const float*)d_in[3];
  float* out = (float*)d_out;
  float* ws = (float*)d_ws;
  // ws layout (floats): stab 1024 | kcum 16384 | ctxT f16[64][64][256] (524288 f)
  // => 2.17 MB, identical footprint to the proven 485us session.
  float* ws_stab = ws;                         // 512 used (1024 reserved)
  float* ws_kcum = ws + 1024;                  // 16384 floats
  f16*   ws_ctxT = (f16*)(ws + 17408);         // 1,048,576 f16
  // d_out scratch (16.9 MB of 67 MB): ctx partials + kcum partials; written by K2,
  // fully consumed by K2c before K3 overwrites d_out. Every byte written before read.
  float* ctx_part  = out;                      // [64bh][2ns][256m][64e] f32
  float* kcum_part = out + 4194304;            // [64bh][2ns][256m] f32
  k1_stab<<<512, 256, 0, stream>>>(k, proj, ws_stab);
  k2_ctx<<<512, 512, 0, stream>>>(k, v, proj, ws_stab, ctx_part, kcum_part);
  k2c_red<<<256, 256, 0, stream>>>(ctx_part, kcum_part, ws_kcum, ws_ctxT);
  k3_out<<<1024, 256, 0, stream>>>(q, proj, ws_kcum, ws_ctxT, out);
}

// Round 4
// 455.845 us; speedup vs baseline: 1.2390x; 1.0491x over previous
//
#include <hip/hip_runtime.h>

#define SEQ 4096
#define CDN 0.35355339059327379f   // 64^(-1/4)
#define DIAGC 0.0625f              // 0.5 * CDN^2
#define KEPS 1e-4f

typedef _Float16 f16;
typedef f16 f16x8 __attribute__((ext_vector_type(8)));
typedef f16 f16x4 __attribute__((ext_vector_type(4)));
typedef float f32x4 __attribute__((ext_vector_type(4)));

#define MFMA16(a, b, c) __builtin_amdgcn_mfma_f32_16x16x32_f16(a, b, c, 0, 0, 0)

// ---- proj staged to LDS: 256 rows x stride 72 f16 (b128 reads, conflict-spread) --
#define PSTR 72

__device__ __forceinline__ void stage_proj(const float* __restrict__ proj, f16* plds) {
  int t = threadIdx.x;
  int mrow = t >> 2;
  int cb = (t & 3) * 16;
#pragma unroll
  for (int p = 0; p < 4; ++p) {
    int m = mrow + p * 64;
    const float4* src = (const float4*)(proj + m * 64 + cb);
    f16* dst = plds + m * PSTR + cb;
#pragma unroll
    for (int i = 0; i < 4; ++i) {
      float4 v = src[i];
      f16x4 h = {(f16)v.x, (f16)v.y, (f16)v.z, (f16)v.w};
      *(f16x4*)(dst + i * 4) = h;
    }
  }
}

__device__ __forceinline__ f16x8 proj_frag(const f16* plds, int mtile, int ks, int lane) {
  int m = (lane & 15) + 16 * mtile;
  return *(const f16x8*)(plds + m * PSTR + ks * 32 + (lane >> 4) * 8);
}

// proj fragment direct from f32 global (used where only 2 frags/wave are needed)
__device__ __forceinline__ f16x8 pfrag32(const float* __restrict__ proj, int mt, int ks, int lane) {
  const float4* p = (const float4*)(proj + (size_t)(16 * mt + (lane & 15)) * 64 + ks * 32 + (lane >> 4) * 8);
  float4 a = p[0], b = p[1];
  f16x8 r = {(f16)a.x, (f16)a.y, (f16)a.z, (f16)a.w,
             (f16)b.x, (f16)b.y, (f16)b.z, (f16)b.w};
  return r;
}

// q/k row fragment scaled by CDN; accumulates raw sum-of-squares into sq
__device__ __forceinline__ f16x8 row_frag(const float* __restrict__ base, int lane, int ks, float& sq) {
  const float4* p = (const float4*)(base + (size_t)(lane & 15) * 64 + ks * 32 + (lane >> 4) * 8);
  float4 a = p[0], b = p[1];
  sq += a.x*a.x + a.y*a.y + a.z*a.z + a.w*a.w + b.x*b.x + b.y*b.y + b.z*b.z + b.w*b.w;
  f16x8 r = {(f16)(a.x*CDN), (f16)(a.y*CDN), (f16)(a.z*CDN), (f16)(a.w*CDN),
             (f16)(b.x*CDN), (f16)(b.y*CDN), (f16)(b.z*CDN), (f16)(b.w*CDN)};
  return r;
}

// ---------------- K2: m-split x ns-split, ONLINE stab (no K1), reg ctx accum --------
// grid = (ns*4 + mc)*64 + bh  (bh-minor => the 16 blocks of a bh share one XCD L2).
// 1024 blocks x 512 thr. 8 waves: wave w -> m-tile (w&3), n-half (w>>2).
// Each wave: online running max M; phi = exp(dd - diag - M); accumulators rescaled
// by exp(M_old - M_new) when M grows. Final per-tile M written for K2c rescale.
#define VSTR 72

// v-transpose staging, lane-major over n: store banks = nl/2 -> all 32 banks, 2-way
__device__ __forceinline__ void stage_vT(const float* __restrict__ vbh, int n, int e8, int nl, f16* dst) {
  const float4* vp = (const float4*)(vbh + (size_t)n * 64 + e8);
  float4 a = vp[0], b = vp[1];
  dst[(e8 + 0) * VSTR + nl] = (f16)a.x;
  dst[(e8 + 1) * VSTR + nl] = (f16)a.y;
  dst[(e8 + 2) * VSTR + nl] = (f16)a.z;
  dst[(e8 + 3) * VSTR + nl] = (f16)a.w;
  dst[(e8 + 4) * VSTR + nl] = (f16)b.x;
  dst[(e8 + 5) * VSTR + nl] = (f16)b.y;
  dst[(e8 + 6) * VSTR + nl] = (f16)b.z;
  dst[(e8 + 7) * VSTR + nl] = (f16)b.w;
}

__global__ __launch_bounds__(512, 4) void k2_ctx(
    const float* __restrict__ kk, const float* __restrict__ vv,
    const float* __restrict__ proj,
    float* __restrict__ ctx_part, float* __restrict__ kcum_part,
    float* __restrict__ stabm, float* __restrict__ vs_part) {
  __shared__ __align__(16) f16 vt[2][64 * VSTR];   // v^T [e][n64], double-buffered
  __shared__ __align__(16) f16 pht[8][16 * 40];    // per-wave phi^T [m16][n32]
  __shared__ __align__(16) float diag_s[8][32];
  __shared__ float red2[4][16];
  __shared__ float stabs[8];
  int bh = blockIdx.x & 63, rest = blockIdx.x >> 6;
  int mc = rest & 3, ns = rest >> 2;               // ns in 0..3
  int w = threadIdx.x >> 6, lane = threadIdx.x & 63;
  int q4 = lane >> 4, l15 = lane & 15;
  int mtl = w & 3, nsub = w >> 2;
  f16x8 pa0 = pfrag32(proj, mc * 4 + mtl, 0, lane);
  f16x8 pa1 = pfrag32(proj, mc * 4 + mtl, 1, lane);
  const float* kbh = kk + (size_t)bh * SEQ * 64;
  const float* vbh = vv + (size_t)bh * SEQ * 64;
  f32x4 actx[4];
  f32x4 akc = {0.f, 0.f, 0.f, 0.f};
#pragma unroll
  for (int i = 0; i < 4; ++i) actx[i] = (f32x4){0.f, 0.f, 0.f, 0.f};
  float vsacc[4] = {0.f, 0.f, 0.f, 0.f};
  float M = -1e30f;
  f16x8 ones = {(f16)1.f, (f16)1.f, (f16)1.f, (f16)1.f,
                (f16)1.f, (f16)1.f, (f16)1.f, (f16)1.f};
  int nl = threadIdx.x & 63, e8 = (threadIdx.x >> 6) * 8;
  int nbase = ns * 1024;
  stage_vT(vbh, nbase + nl, e8, nl, &vt[0][0]);
  __syncthreads();
#pragma unroll 1
  for (int it = 0; it < 16; ++it) {
    int n0 = nbase + it * 64;
    if (it < 15) stage_vT(vbh, n0 + 64 + nl, e8, nl, &vt[(it & 1) ^ 1][0]);
    const f16* vcur = &vt[it & 1][0];
    // k row frags (A-operand) + per-row diag for this wave's 32 rows
    f16x8 ak[2][2];
    float dg[2];
#pragma unroll
    for (int nt = 0; nt < 2; ++nt) {
      float sq = 0.f;
      const float* kb = kbh + (size_t)(n0 + nsub * 32 + nt * 16) * 64;
      ak[nt][0] = row_frag(kb, lane, 0, sq);
      ak[nt][1] = row_frag(kb, lane, 1, sq);
      sq += __shfl_xor(sq, 16, 64);
      sq += __shfl_xor(sq, 32, 64);
      dg[nt] = sq * DIAGC;
    }
    if (lane < 16) { diag_s[w][lane] = dg[0]; diag_s[w][16 + lane] = dg[1]; }
    // dd for both 16-row tiles, then online-max update
    f32x4 accv[2];
#pragma unroll
    for (int nt = 0; nt < 2; ++nt) {
      f32x4 a = {0.f, 0.f, 0.f, 0.f};
      a = MFMA16(ak[nt][0], pa0, a);
      a = MFMA16(ak[nt][1], pa1, a);
      accv[nt] = a;
    }
    float tm = fmaxf(fmaxf(fmaxf(accv[0][0], accv[0][1]), fmaxf(accv[0][2], accv[0][3])),
                     fmaxf(fmaxf(accv[1][0], accv[1][1]), fmaxf(accv[1][2], accv[1][3])));
#pragma unroll
    for (int m = 1; m < 64; m <<= 1) tm = fmaxf(tm, __shfl_xor(tm, m, 64));
    if (tm > M) {  // wave-uniform
      float rs = __expf(M - tm);
      akc *= rs;
#pragma unroll
      for (int et = 0; et < 4; ++et) actx[et] *= rs;
      M = tm;
    }
    // phi = exp(dd - diag - M)  (NO eps here; eps handled exactly in K2c)
#pragma unroll
    for (int nt = 0; nt < 2; ++nt) {
      float4 dgv = ((const float4*)&diag_s[w][0])[nt * 4 + q4];
      f16x4 ph;
      ph[0] = (f16)__expf(accv[nt][0] - dgv.x - M);
      ph[1] = (f16)__expf(accv[nt][1] - dgv.y - M);
      ph[2] = (f16)__expf(accv[nt][2] - dgv.z - M);
      ph[3] = (f16)__expf(accv[nt][3] - dgv.w - M);
      *(f16x4*)(&pht[w][l15 * 40 + nt * 16 + q4 * 4]) = ph;
    }
    f16x8 bv[4];
#pragma unroll
    for (int et = 0; et < 4; ++et)
      bv[et] = *(const f16x8*)(vcur + (l15 + 16 * et) * VSTR + nsub * 32 + q4 * 8);
    // v colsum (for the eps*colsum(v) term) - cheap VALU, 2 waves only
    if (mc == 0 && mtl == 0) {
#pragma unroll
      for (int et = 0; et < 4; ++et) {
        float s = 0.f;
#pragma unroll
        for (int j = 0; j < 8; ++j) s += (float)bv[et][j];
        vsacc[et] += s;
      }
    }
    f16x8 aph = *(const f16x8*)(&pht[w][l15 * 40 + q4 * 8]);
    akc = MFMA16(aph, ones, akc);
#pragma unroll
    for (int et = 0; et < 4; ++et) actx[et] = MFMA16(aph, bv[et], actx[et]);
    __syncthreads();  // next vt buffer ready; protects vt before next overwrite
  }
  // ---- epilogue: align scales across the nsub pair, reduce, store partials ----
  if (lane == 0) stabs[w] = M;
  __syncthreads();
  float Mp = stabs[w ^ 4];
  float Mt = fmaxf(M, Mp);
  {
    float sc = __expf(M - Mt);
    akc *= sc;
#pragma unroll
    for (int et = 0; et < 4; ++et) actx[et] *= sc;
  }
  // v colsum store (independent of rescale)
  if (mc == 0 && mtl == 0) {
#pragma unroll
    for (int et = 0; et < 4; ++et) {
      float s = vsacc[et];
      s += __shfl_xor(s, 16, 64);
      s += __shfl_xor(s, 32, 64);
      if (lane < 16)
        vs_part[(size_t)bh * 512 + (ns * 2 + nsub) * 64 + lane + 16 * et] = s;
    }
  }
  float* red = (float*)&vt[0][0];  // 16 KB needed, 18 KB available (vt dead)
  if (nsub == 1) {
#pragma unroll
    for (int et = 0; et < 4; ++et)
#pragma unroll
      for (int r = 0; r < 4; ++r)
        red[mtl * 1024 + (q4 * 4 + r) * 64 + l15 + 16 * et] = actx[et][r];
    if (l15 == 0) {
#pragma unroll
      for (int r = 0; r < 4; ++r) red2[mtl][q4 * 4 + r] = akc[r];
    }
  }
  __syncthreads();
  if (nsub == 0) {
    float* cp = ctx_part + (((size_t)bh * 4 + ns) * 256 + mc * 64 + mtl * 16) * 64;
#pragma unroll
    for (int et = 0; et < 4; ++et)
#pragma unroll
      for (int r = 0; r < 4; ++r)
        cp[(size_t)(q4 * 4 + r) * 64 + l15 + 16 * et] =
            actx[et][r] + red[mtl * 1024 + (q4 * 4 + r) * 64 + l15 + 16 * et];
    if (l15 == 0) {
#pragma unroll
      for (int r = 0; r < 4; ++r)
        kcum_part[((size_t)bh * 4 + ns) * 256 + mc * 64 + mtl * 16 + q4 * 4 + r] =
            akc[r] + red2[mtl][q4 * 4 + r];
    }
    if (lane == 0) stabm[(size_t)bh * 64 + ns * 16 + mc * 4 + mtl] = Mt;
  }
}

// ---------------- K2c: rescale+sum 4 ns-partials -> fp32 kcum + f16 ctxT [e][m] ----
// grid = mq*64 + bh (bh-minor => same XCD as producers => partials are L2 hits).
// ctx_true = sum_ns e^{M[ns][tile]-S} * A_ns + eps*colsum(v);  kcum += eps*4096.
__global__ __launch_bounds__(256) void k2c_red(
    const float* __restrict__ ctx_part, const float* __restrict__ kcum_part,
    const float* __restrict__ stabm, const float* __restrict__ vs_part,
    float* __restrict__ ws_kcum, f16* __restrict__ ws_ctxT) {
  __shared__ float tile[64 * 65];
  __shared__ float sred[64];
  __shared__ float vsum_l[64];
  __shared__ float fac[4][4];  // [ns][tile-in-mq]
  int bh = blockIdx.x & 63, mq = blockIdx.x >> 6;
  int t = threadIdx.x;
  if (t < 64) {
    sred[t] = stabm[(size_t)bh * 64 + t];  // [ns4][tile16]
    float vs = 0.f;
#pragma unroll
    for (int i = 0; i < 8; ++i) vs += vs_part[(size_t)bh * 512 + i * 64 + t];
    vsum_l[t] = vs;
  }
  __syncthreads();
  float S = -1e30f;
#pragma unroll
  for (int i = 0; i < 64; ++i) S = fmaxf(S, sred[i]);  // uniform broadcast reads
  if (t < 16) fac[t >> 2][t & 3] = __expf(sred[(t >> 2) * 16 + mq * 4 + (t & 3)] - S);
  __syncthreads();
  const float* cp = ctx_part + ((size_t)bh * 4 * 256 + mq * 64) * 64;
#pragma unroll
  for (int i = 0; i < 16; ++i) {
    int idx = t + i * 256;       // over [64m x 64e]
    int ml = idx >> 6, e = idx & 63;
    int tl = ml >> 4;
    float acc = KEPS * vsum_l[e];
#pragma unroll
    for (int ns = 0; ns < 4; ++ns)
      acc += fac[ns][tl] * cp[(size_t)ns * 16384 + idx];
    tile[ml * 65 + e] = acc;
  }
  if (t < 64) {
    int tl = t >> 4;
    float acc = KEPS * 4096.f;
#pragma unroll
    for (int ns = 0; ns < 4; ++ns)
      acc += fac[ns][tl] * kcum_part[((size_t)bh * 4 + ns) * 256 + mq * 64 + t];
    ws_kcum[bh * 256 + mq * 64 + t] = acc;
  }
  __syncthreads();
  f16* ct = ws_ctxT + (size_t)bh * 16384 + mq * 64;
  int mj = t & 63, eg = t >> 6;
#pragma unroll
  for (int i = 0; i < 16; ++i) {
    int e = eg + i * 4;
    ct[(size_t)e * 256 + mj] = (f16)tile[mj * 65 + e];
  }
}

// ---------------- K3: dd_q -> phi_q -> out = (phi_q @ ctx) / (phi_q . kcum) --------
// proj via LDS (plds); ctxT staged once into LDS; kcum in LDS; phi in m-quarters.
// LDS total 80,896 B -> 2 blocks/CU.
#define CSTR 264

__global__ __launch_bounds__(256, 2) void k3_out(
    const float* __restrict__ qq, const float* __restrict__ proj,
    const float* __restrict__ ws_kcum, const f16* __restrict__ ws_ctxT,
    float* __restrict__ out) {
  __shared__ __align__(16) f16 plds[256 * PSTR];   // 36864 B
  __shared__ __align__(16) f16 ctx_l[64 * CSTR];   // 33792 B
  __shared__ __align__(16) f16 phq[4][16 * 72];    // 9216 B, per-wave quarter buffer
  __shared__ __align__(16) float kcl[256];         // 1024 B
  int bh = blockIdx.x >> 4, blk = blockIdx.x & 15;
  int t = threadIdx.x;
  stage_proj(proj, plds);
  kcl[t] = ws_kcum[bh * 256 + t];
  {
    const f16* cb = ws_ctxT + (size_t)bh * 16384;
#pragma unroll
    for (int i = 0; i < 8; ++i) {
      int c = t + i * 256;
      int e = c >> 5, mo = (c & 31) * 8;
      *(f16x8*)(ctx_l + e * CSTR + mo) = *(const f16x8*)(cb + e * 256 + mo);
    }
  }
  int w = t >> 6, lane = t & 63;
  int q4 = lane >> 4, l15 = lane & 15;
  const float* qbh = qq + (size_t)bh * SEQ * 64;
  float* obh = out + (size_t)bh * SEQ * 64;
  __syncthreads();
#pragma unroll 1
  for (int it = 0; it < 4; ++it) {
    int n0 = blk * 256 + w * 64 + it * 16;
    float sq = 0.f;
    f16x8 bq0 = row_frag(qbh + (size_t)n0 * 64, lane, 0, sq);
    f16x8 bq1 = row_frag(qbh + (size_t)n0 * 64, lane, 1, sq);
    sq += __shfl_xor(sq, 16, 64);
    sq += __shfl_xor(sq, 32, 64);
    float diag = sq * DIAGC;  // diag for column n = n0 + l15 (ddT orientation)
    f32x4 dd[16];
#pragma unroll
    for (int mt = 0; mt < 16; ++mt) {
      f32x4 acc = {0.f, 0.f, 0.f, 0.f};
      acc = MFMA16(proj_frag(plds, mt, 0, lane), bq0, acc);
      acc = MFMA16(proj_frag(plds, mt, 1, lane), bq1, acc);
      dd[mt] = acc;  // ddT: row m = 16*mt + 4*q4 + reg, col n = l15
    }
    float st = -1e30f;
#pragma unroll
    for (int mt = 0; mt < 16; ++mt)
      st = fmaxf(st, fmaxf(fmaxf(dd[mt][0], dd[mt][1]), fmaxf(dd[mt][2], dd[mt][3])));
    st = fmaxf(st, __shfl_xor(st, 16, 64));
    st = fmaxf(st, __shfl_xor(st, 32, 64));  // per-q-row max
    float dacc = 0.f;
    f32x4 ao[4];
#pragma unroll
    for (int r = 0; r < 4; ++r) ao[r] = (f32x4){0.f, 0.f, 0.f, 0.f};
#pragma unroll
    for (int qtr = 0; qtr < 4; ++qtr) {
#pragma unroll
      for (int m2 = 0; m2 < 4; ++m2) {
        int mt = qtr * 4 + m2;
        float4 kc = ((const float4*)kcl)[mt * 4 + q4];
        float e0 = __expf(dd[mt][0] - diag - st) + KEPS;
        float e1 = __expf(dd[mt][1] - diag - st) + KEPS;
        float e2 = __expf(dd[mt][2] - diag - st) + KEPS;
        float e3 = __expf(dd[mt][3] - diag - st) + KEPS;
        dacc += e0 * kc.x + e1 * kc.y + e2 * kc.z + e3 * kc.w;
        f16x4 ph;
        ph[0] = (f16)e0; ph[1] = (f16)e1; ph[2] = (f16)e2; ph[3] = (f16)e3;
        *(f16x4*)(&phq[w][l15 * 72 + m2 * 16 + q4 * 4]) = ph;
      }
      // wave-local write->read (lockstep, compiler inserts lgkmcnt)
#pragma unroll
      for (int kl = 0; kl < 2; ++kl) {
        int ks2 = qtr * 2 + kl;
        f16x8 bph = *(const f16x8*)(&phq[w][l15 * 72 + kl * 32 + q4 * 8]);
#pragma unroll
        for (int rte = 0; rte < 4; ++rte) {
          f16x8 act = *(const f16x8*)(ctx_l + (l15 + 16 * rte) * CSTR + ks2 * 32 + q4 * 8);
          ao[rte] = MFMA16(act, bph, ao[rte]);  // outT: row e, col n
        }
      }
    }
    dacc += __shfl_xor(dacc, 16, 64);
    dacc += __shfl_xor(dacc, 32, 64);
    float dinv = 1.0f / dacc;
#pragma unroll
    for (int rte = 0; rte < 4; ++rte) {
      float4 o;
      o.x = ao[rte][0] * dinv;
      o.y = ao[rte][1] * dinv;
      o.z = ao[rte][2] * dinv;
      o.w = ao[rte][3] * dinv;
      *(float4*)(obh + (size_t)(n0 + l15) * 64 + rte * 16 + q4 * 4) = o;
    }
  }
}

extern "C" void kernel_launch(void* const* d_in, const int* in_sizes, int n_in,
                              void* d_out, int out_size, void* d_ws, size_t ws_size,
                              hipStream_t stream) {
  const float* q = (const float*)d_in[0];
  const float* k = (const float*)d_in[1];
  const float* v = (const float*)d_in[2];
  const float* proj = (const float*)d_in[3];
  float* out = (float*)d_out;
  float* ws = (float*)d_ws;
  // ws layout (floats): [reserved 1024] | kcum 16384 | ctxT f16 (524288 f)
  // => 2.17 MB, identical footprint/offsets to the proven sessions.
  float* ws_kcum = ws + 1024;                  // 16384 floats
  f16*   ws_ctxT = (f16*)(ws + 17408);         // 1,048,576 f16
  // d_out scratch (17.2 MB of 67 MB): written by K2, fully consumed by K2c before
  // K3 overwrites every element of d_out. Every scratch byte written before read.
  float* ctx_part  = out;                      // [64bh][4ns][256m][64e] f32
  float* kcum_part = out + 4194304;            // [64bh][4ns][256m]
  float* stabm     = out + 4259840;            // [64bh][4ns][16tile]
  float* vs_part   = out + 4263936;            // [64bh][4ns][2nsub][64e]
  k2_ctx<<<1024, 512, 0, stream>>>(k, v, proj, ctx_part, kcum_part, stabm, vs_part);
  k2c_red<<<256, 256, 0, stream>>>(ctx_part, kcum_part, stabm, vs_part, ws_kcum, ws_ctxT);
  k3_out<<<1024, 256, 0, stream>>>(q, proj, ws_kcum, ws_ctxT, out);
}

// Round 7
// 396.200 us; speedup vs baseline: 1.4256x; 1.1505x over previous
//
#include <hip/hip_runtime.h>

#define SEQ 4096
#define CDN 0.35355339059327379f   // 64^(-1/4)
#define DIAGC 0.0625f              // 0.5 * CDN^2
#define KEPS 1e-4f

typedef _Float16 f16;
typedef f16 f16x8 __attribute__((ext_vector_type(8)));
typedef f16 f16x4 __attribute__((ext_vector_type(4)));
typedef float f32x4 __attribute__((ext_vector_type(4)));

#define MFMA16(a, b, c) __builtin_amdgcn_mfma_f32_16x16x32_f16(a, b, c, 0, 0, 0)

// ---- proj staged to LDS: 256 rows x stride 72 f16 (b128 reads, conflict-spread) --
#define PSTR 72

__device__ __forceinline__ void stage_proj(const float* __restrict__ proj, f16* plds) {
  int t = threadIdx.x;
  int mrow = t >> 2;
  int cb = (t & 3) * 16;
#pragma unroll
  for (int p = 0; p < 4; ++p) {
    int m = mrow + p * 64;
    const float4* src = (const float4*)(proj + m * 64 + cb);
    f16* dst = plds + m * PSTR + cb;
#pragma unroll
    for (int i = 0; i < 4; ++i) {
      float4 v = src[i];
      f16x4 h = {(f16)v.x, (f16)v.y, (f16)v.z, (f16)v.w};
      *(f16x4*)(dst + i * 4) = h;
    }
  }
}

__device__ __forceinline__ f16x8 proj_frag(const f16* plds, int mtile, int ks, int lane) {
  int m = (lane & 15) + 16 * mtile;
  return *(const f16x8*)(plds + m * PSTR + ks * 32 + (lane >> 4) * 8);
}

// proj fragment direct from f32 global, scaled by CDN (for K2: 2 frags/wave)
__device__ __forceinline__ f16x8 pfrag32s(const float* __restrict__ proj, int mt, int ks, int lane) {
  const float4* p = (const float4*)(proj + (size_t)(16 * mt + (lane & 15)) * 64 + ks * 32 + (lane >> 4) * 8);
  float4 a = p[0], b = p[1];
  f16x8 r = {(f16)(a.x*CDN), (f16)(a.y*CDN), (f16)(a.z*CDN), (f16)(a.w*CDN),
             (f16)(b.x*CDN), (f16)(b.y*CDN), (f16)(b.z*CDN), (f16)(b.w*CDN)};
  return r;
}

// q row fragment scaled by CDN; accumulates raw sum-of-squares into sq (K3)
__device__ __forceinline__ f16x8 row_frag(const float* __restrict__ base, int lane, int ks, float& sq) {
  const float4* p = (const float4*)(base + (size_t)(lane & 15) * 64 + ks * 32 + (lane >> 4) * 8);
  float4 a = p[0], b = p[1];
  sq += a.x*a.x + a.y*a.y + a.z*a.z + a.w*a.w + b.x*b.x + b.y*b.y + b.z*b.z + b.w*b.w;
  f16x8 r = {(f16)(a.x*CDN), (f16)(a.y*CDN), (f16)(a.z*CDN), (f16)(a.w*CDN),
             (f16)(b.x*CDN), (f16)(b.y*CDN), (f16)(b.z*CDN), (f16)(b.w*CDN)};
  return r;
}

// ---------------- K2: m-split x ns-split, ONLINE stab, k+v staged in LDS -----------
// grid = (ns*4 + mc)*64 + bh (bh-minor => 16 blocks of a bh share one XCD L2).
// 1024 blocks x 512 thr. 8 waves: wave w -> m-tile (w&3), n-half (w>>2).
// k staged ONCE per block (raw f16, CDN folded into proj frags); diag computed at
// staging time; all double-buffered with ONE barrier per iteration.
#define KSTR 72

// stage k row-major (+ per-row diag) and v transposed, for rows [n0, n0+64)
__device__ __forceinline__ void stage_kv(const float* __restrict__ kbh,
                                         const float* __restrict__ vbh,
                                         int n0, f16* ktb, f16* vtb,
                                         float* diagb, int t) {
  // k: thread t -> row t>>3, col chunk (t&7)*8
  int r = t >> 3;
  int c8 = (t & 7) * 8;
  const float4* kp = (const float4*)(kbh + (size_t)(n0 + r) * 64 + c8);
  float4 a = kp[0], b = kp[1];
  float sq = a.x*a.x + a.y*a.y + a.z*a.z + a.w*a.w + b.x*b.x + b.y*b.y + b.z*b.z + b.w*b.w;
  f16x8 h = {(f16)a.x, (f16)a.y, (f16)a.z, (f16)a.w,
             (f16)b.x, (f16)b.y, (f16)b.z, (f16)b.w};
  *(f16x8*)(ktb + r * KSTR + c8) = h;
  sq += __shfl_xor(sq, 1, 64);
  sq += __shfl_xor(sq, 2, 64);
  sq += __shfl_xor(sq, 4, 64);
  if ((t & 7) == 0) diagb[r] = sq * DIAGC;
  // v transposed: thread t -> row t&63, e-chunk (t>>6)*8 (bank-spread stores)
  int nl = t & 63, e8 = (t >> 6) * 8;
  const float4* vp = (const float4*)(vbh + (size_t)(n0 + nl) * 64 + e8);
  float4 va = vp[0], vb = vp[1];
  vtb[(e8 + 0) * KSTR + nl] = (f16)va.x;
  vtb[(e8 + 1) * KSTR + nl] = (f16)va.y;
  vtb[(e8 + 2) * KSTR + nl] = (f16)va.z;
  vtb[(e8 + 3) * KSTR + nl] = (f16)va.w;
  vtb[(e8 + 4) * KSTR + nl] = (f16)vb.x;
  vtb[(e8 + 5) * KSTR + nl] = (f16)vb.y;
  vtb[(e8 + 6) * KSTR + nl] = (f16)vb.z;
  vtb[(e8 + 7) * KSTR + nl] = (f16)vb.w;
}

__global__ __launch_bounds__(512, 4) void k2_ctx(
    const float* __restrict__ kk, const float* __restrict__ vv,
    const float* __restrict__ proj,
    float* __restrict__ ctx_part, float* __restrict__ kcum_part,
    float* __restrict__ stabm, float* __restrict__ vs_part) {
  __shared__ __align__(16) f16 kt[2][64 * KSTR];   // 18432 B
  __shared__ __align__(16) f16 vt[2][64 * KSTR];   // 18432 B
  __shared__ __align__(16) f16 pht[8][16 * 40];    // 10240 B
  __shared__ float diag_all[2][64];
  __shared__ float red2[4][16];
  __shared__ float stabs[8];
  int bh = blockIdx.x & 63, rest = blockIdx.x >> 6;
  int mc = rest & 3, ns = rest >> 2;               // ns in 0..3
  int t = threadIdx.x;
  int w = t >> 6, lane = t & 63;
  int q4 = lane >> 4, l15 = lane & 15;
  int mtl = w & 3, nsub = w >> 2;
  f16x8 pa0 = pfrag32s(proj, mc * 4 + mtl, 0, lane);   // CDN-scaled proj frags
  f16x8 pa1 = pfrag32s(proj, mc * 4 + mtl, 1, lane);
  const float* kbh = kk + (size_t)bh * SEQ * 64;
  const float* vbh = vv + (size_t)bh * SEQ * 64;
  f32x4 actx[4];
  f32x4 akc = {0.f, 0.f, 0.f, 0.f};
#pragma unroll
  for (int i = 0; i < 4; ++i) actx[i] = (f32x4){0.f, 0.f, 0.f, 0.f};
  float vsacc[4] = {0.f, 0.f, 0.f, 0.f};
  float M = -1e30f;
  f16x8 ones = {(f16)1.f, (f16)1.f, (f16)1.f, (f16)1.f,
                (f16)1.f, (f16)1.f, (f16)1.f, (f16)1.f};
  int nbase = ns * 1024;
  stage_kv(kbh, vbh, nbase, &kt[0][0], &vt[0][0], &diag_all[0][0], t);
  __syncthreads();
#pragma unroll 1
  for (int it = 0; it < 16; ++it) {
    int n0 = nbase + it * 64;
    int cur = it & 1;
    if (it < 15)
      stage_kv(kbh, vbh, n0 + 64, &kt[cur ^ 1][0], &vt[cur ^ 1][0], &diag_all[cur ^ 1][0], t);
    const f16* ktc = &kt[cur][0];
    const f16* vcur = &vt[cur][0];
    // k frags for this wave's 32 rows (b128 LDS reads, shared across mtl waves)
    f16x8 ak[2][2];
#pragma unroll
    for (int nt = 0; nt < 2; ++nt) {
      ak[nt][0] = *(const f16x8*)(ktc + (nsub * 32 + nt * 16 + l15) * KSTR + q4 * 8);
      ak[nt][1] = *(const f16x8*)(ktc + (nsub * 32 + nt * 16 + l15) * KSTR + 32 + q4 * 8);
    }
    // dd for both 16-row tiles, then online-max update
    f32x4 accv[2];
#pragma unroll
    for (int nt = 0; nt < 2; ++nt) {
      f32x4 a = {0.f, 0.f, 0.f, 0.f};
      a = MFMA16(ak[nt][0], pa0, a);
      a = MFMA16(ak[nt][1], pa1, a);
      accv[nt] = a;
    }
    float tm = fmaxf(fmaxf(fmaxf(accv[0][0], accv[0][1]), fmaxf(accv[0][2], accv[0][3])),
                     fmaxf(fmaxf(accv[1][0], accv[1][1]), fmaxf(accv[1][2], accv[1][3])));
#pragma unroll
    for (int m = 1; m < 64; m <<= 1) tm = fmaxf(tm, __shfl_xor(tm, m, 64));
    if (tm > M) {  // wave-uniform
      float rs = __expf(M - tm);
      akc *= rs;
#pragma unroll
      for (int et = 0; et < 4; ++et) actx[et] *= rs;
      M = tm;
    }
    // phi = exp(dd - diag - M)  (NO eps; eps handled exactly in K2c)
#pragma unroll
    for (int nt = 0; nt < 2; ++nt) {
      float4 dgv = ((const float4*)&diag_all[cur][0])[nsub * 8 + nt * 4 + q4];
      f16x4 ph;
      ph[0] = (f16)__expf(accv[nt][0] - dgv.x - M);
      ph[1] = (f16)__expf(accv[nt][1] - dgv.y - M);
      ph[2] = (f16)__expf(accv[nt][2] - dgv.z - M);
      ph[3] = (f16)__expf(accv[nt][3] - dgv.w - M);
      *(f16x4*)(&pht[w][l15 * 40 + nt * 16 + q4 * 4]) = ph;
    }
    f16x8 bv[4];
#pragma unroll
    for (int et = 0; et < 4; ++et)
      bv[et] = *(const f16x8*)(vcur + (l15 + 16 * et) * KSTR + nsub * 32 + q4 * 8);
    // v colsum (for the eps*colsum(v) term) - 2 waves only
    if (mc == 0 && mtl == 0) {
#pragma unroll
      for (int et = 0; et < 4; ++et) {
        float s = 0.f;
#pragma unroll
        for (int j = 0; j < 8; ++j) s += (float)bv[et][j];
        vsacc[et] += s;
      }
    }
    f16x8 aph = *(const f16x8*)(&pht[w][l15 * 40 + q4 * 8]);
    akc = MFMA16(aph, ones, akc);
#pragma unroll
    for (int et = 0; et < 4; ++et) actx[et] = MFMA16(aph, bv[et], actx[et]);
    __syncthreads();  // staged buffers ready; protects cur buffers for next overwrite
  }
  // ---- epilogue: align scales across the nsub pair, reduce, store partials ----
  if (lane == 0) stabs[w] = M;
  __syncthreads();
  float Mp = stabs[w ^ 4];
  float Mt = fmaxf(M, Mp);
  {
    float sc = __expf(M - Mt);
    akc *= sc;
#pragma unroll
    for (int et = 0; et < 4; ++et) actx[et] *= sc;
  }
  if (mc == 0 && mtl == 0) {
#pragma unroll
    for (int et = 0; et < 4; ++et) {
      float s = vsacc[et];
      s += __shfl_xor(s, 16, 64);
      s += __shfl_xor(s, 32, 64);
      if (lane < 16)
        vs_part[(size_t)bh * 512 + (ns * 2 + nsub) * 64 + lane + 16 * et] = s;
    }
  }
  float* red = (float*)&kt[0][0];  // 16 KB needed, 18.4 KB available (kt dead)
  if (nsub == 1) {
#pragma unroll
    for (int et = 0; et < 4; ++et)
#pragma unroll
      for (int r = 0; r < 4; ++r)
        red[mtl * 1024 + (q4 * 4 + r) * 64 + l15 + 16 * et] = actx[et][r];
    if (l15 == 0) {
#pragma unroll
      for (int r = 0; r < 4; ++r) red2[mtl][q4 * 4 + r] = akc[r];
    }
  }
  __syncthreads();
  if (nsub == 0) {
    float* cp = ctx_part + (((size_t)bh * 4 + ns) * 256 + mc * 64 + mtl * 16) * 64;
#pragma unroll
    for (int et = 0; et < 4; ++et)
#pragma unroll
      for (int r = 0; r < 4; ++r)
        cp[(size_t)(q4 * 4 + r) * 64 + l15 + 16 * et] =
            actx[et][r] + red[mtl * 1024 + (q4 * 4 + r) * 64 + l15 + 16 * et];
    if (l15 == 0) {
#pragma unroll
      for (int r = 0; r < 4; ++r)
        kcum_part[((size_t)bh * 4 + ns) * 256 + mc * 64 + mtl * 16 + q4 * 4 + r] =
            akc[r] + red2[mtl][q4 * 4 + r];
    }
    if (lane == 0) stabm[(size_t)bh * 64 + ns * 16 + mc * 4 + mtl] = Mt;
  }
}

// ---------------- K2c: rescale+sum 4 ns-partials -> fp32 kcum + f16 ctxT [e][m] ----
__global__ __launch_bounds__(256) void k2c_red(
    const float* __restrict__ ctx_part, const float* __restrict__ kcum_part,
    const float* __restrict__ stabm, const float* __restrict__ vs_part,
    float* __restrict__ ws_kcum, f16* __restrict__ ws_ctxT) {
  __shared__ float tile[64 * 65];
  __shared__ float sred[64];
  __shared__ float vsum_l[64];
  __shared__ float fac[4][4];  // [ns][tile-in-mq]
  int bh = blockIdx.x & 63, mq = blockIdx.x >> 6;
  int t = threadIdx.x;
  if (t < 64) {
    sred[t] = stabm[(size_t)bh * 64 + t];  // [ns4][tile16]
    float vs = 0.f;
#pragma unroll
    for (int i = 0; i < 8; ++i) vs += vs_part[(size_t)bh * 512 + i * 64 + t];
    vsum_l[t] = vs;
  }
  __syncthreads();
  float S = -1e30f;
#pragma unroll
  for (int i = 0; i < 64; ++i) S = fmaxf(S, sred[i]);
  if (t < 16) fac[t >> 2][t & 3] = __expf(sred[(t >> 2) * 16 + mq * 4 + (t & 3)] - S);
  __syncthreads();
  const float* cp = ctx_part + ((size_t)bh * 4 * 256 + mq * 64) * 64;
#pragma unroll
  for (int i = 0; i < 16; ++i) {
    int idx = t + i * 256;       // over [64m x 64e]
    int ml = idx >> 6, e = idx & 63;
    int tl = ml >> 4;
    float acc = KEPS * vsum_l[e];
#pragma unroll
    for (int ns = 0; ns < 4; ++ns)
      acc += fac[ns][tl] * cp[(size_t)ns * 16384 + idx];
    tile[ml * 65 + e] = acc;
  }
  if (t < 64) {
    int tl = t >> 4;
    float acc = KEPS * 4096.f;
#pragma unroll
    for (int ns = 0; ns < 4; ++ns)
      acc += fac[ns][tl] * kcum_part[((size_t)bh * 4 + ns) * 256 + mq * 64 + t];
    ws_kcum[bh * 256 + mq * 64 + t] = acc;
  }
  __syncthreads();
  f16* ct = ws_ctxT + (size_t)bh * 16384 + mq * 64;
  int mj = t & 63, eg = t >> 6;
#pragma unroll
  for (int i = 0; i < 16; ++i) {
    int e = eg + i * 4;
    ct[(size_t)e * 256 + mj] = (f16)tile[mj * 65 + e];
  }
}

// ---------------- K3: dd_q -> phi_q -> out, TWO-PASS (max, then recompute+exp) -----
// Pass 1 tracks only the per-row max (st) -> no dd[16] array -> no scratch spill.
// Pass 2 recomputes dd (bit-identical MFMA) and exponentiates straight into phq.
// Nontemporal out stores (written once, never re-read -> no RFO/allocate).
#define CSTR 264

__global__ __launch_bounds__(256, 2) void k3_out(
    const float* __restrict__ qq, const float* __restrict__ proj,
    const float* __restrict__ ws_kcum, const f16* __restrict__ ws_ctxT,
    float* __restrict__ out) {
  __shared__ __align__(16) f16 plds[256 * PSTR];   // 36864 B
  __shared__ __align__(16) f16 ctx_l[64 * CSTR];   // 33792 B
  __shared__ __align__(16) f16 phq[4][16 * 72];    // 9216 B, per-wave quarter buffer
  __shared__ __align__(16) float kcl[256];         // 1024 B
  int bh = blockIdx.x >> 4, blk = blockIdx.x & 15;
  int t = threadIdx.x;
  stage_proj(proj, plds);
  kcl[t] = ws_kcum[bh * 256 + t];
  {
    const f16* cb = ws_ctxT + (size_t)bh * 16384;
#pragma unroll
    for (int i = 0; i < 8; ++i) {
      int c = t + i * 256;
      int e = c >> 5, mo = (c & 31) * 8;
      *(f16x8*)(ctx_l + e * CSTR + mo) = *(const f16x8*)(cb + e * 256 + mo);
    }
  }
  int w = t >> 6, lane = t & 63;
  int q4 = lane >> 4, l15 = lane & 15;
  const float* qbh = qq + (size_t)bh * SEQ * 64;
  float* obh = out + (size_t)bh * SEQ * 64;
  __syncthreads();
#pragma unroll 1
  for (int it = 0; it < 4; ++it) {
    int n0 = blk * 256 + w * 64 + it * 16;
    float sq = 0.f;
    f16x8 bq0 = row_frag(qbh + (size_t)n0 * 64, lane, 0, sq);
    f16x8 bq1 = row_frag(qbh + (size_t)n0 * 64, lane, 1, sq);
    sq += __shfl_xor(sq, 16, 64);
    sq += __shfl_xor(sq, 32, 64);
    float diag = sq * DIAGC;  // diag for column n = n0 + l15 (ddT orientation)
    // pass 1: per-row max only (no dd array kept live)
    float st = -1e30f;
#pragma unroll
    for (int mt = 0; mt < 16; ++mt) {
      f32x4 acc = {0.f, 0.f, 0.f, 0.f};
      acc = MFMA16(proj_frag(plds, mt, 0, lane), bq0, acc);
      acc = MFMA16(proj_frag(plds, mt, 1, lane), bq1, acc);
      st = fmaxf(st, fmaxf(fmaxf(acc[0], acc[1]), fmaxf(acc[2], acc[3])));
    }
    st = fmaxf(st, __shfl_xor(st, 16, 64));
    st = fmaxf(st, __shfl_xor(st, 32, 64));  // per-q-row max
    // pass 2: recompute dd tile-by-tile (bit-identical), exp -> phq -> PV
    float dacc = 0.f;
    f32x4 ao[4];
#pragma unroll
    for (int r = 0; r < 4; ++r) ao[r] = (f32x4){0.f, 0.f, 0.f, 0.f};
#pragma unroll
    for (int qtr = 0; qtr < 4; ++qtr) {
#pragma unroll
      for (int m2 = 0; m2 < 4; ++m2) {
        int mt = qtr * 4 + m2;
        f32x4 acc = {0.f, 0.f, 0.f, 0.f};
        acc = MFMA16(proj_frag(plds, mt, 0, lane), bq0, acc);
        acc = MFMA16(proj_frag(plds, mt, 1, lane), bq1, acc);
        float4 kc = ((const float4*)kcl)[mt * 4 + q4];
        float e0 = __expf(acc[0] - diag - st) + KEPS;
        float e1 = __expf(acc[1] - diag - st) + KEPS;
        float e2 = __expf(acc[2] - diag - st) + KEPS;
        float e3 = __expf(acc[3] - diag - st) + KEPS;
        dacc += e0 * kc.x + e1 * kc.y + e2 * kc.z + e3 * kc.w;
        f16x4 ph;
        ph[0] = (f16)e0; ph[1] = (f16)e1; ph[2] = (f16)e2; ph[3] = (f16)e3;
        *(f16x4*)(&phq[w][l15 * 72 + m2 * 16 + q4 * 4]) = ph;
      }
      // wave-local write->read (lockstep, compiler inserts lgkmcnt)
#pragma unroll
      for (int kl = 0; kl < 2; ++kl) {
        int ks2 = qtr * 2 + kl;
        f16x8 bph = *(const f16x8*)(&phq[w][l15 * 72 + kl * 32 + q4 * 8]);
#pragma unroll
        for (int rte = 0; rte < 4; ++rte) {
          f16x8 act = *(const f16x8*)(ctx_l + (l15 + 16 * rte) * CSTR + ks2 * 32 + q4 * 8);
          ao[rte] = MFMA16(act, bph, ao[rte]);  // outT: row e, col n
        }
      }
    }
    dacc += __shfl_xor(dacc, 16, 64);
    dacc += __shfl_xor(dacc, 32, 64);
    float dinv = 1.0f / dacc;
#pragma unroll
    for (int rte = 0; rte < 4; ++rte) {
      f32x4 o = ao[rte] * dinv;
      __builtin_nontemporal_store(o, (f32x4*)(obh + (size_t)(n0 + l15) * 64 + rte * 16 + q4 * 4));
    }
  }
}

extern "C" void kernel_launch(void* const* d_in, const int* in_sizes, int n_in,
                              void* d_out, int out_size, void* d_ws, size_t ws_size,
                              hipStream_t stream) {
  const float* q = (const float*)d_in[0];
  const float* k = (const float*)d_in[1];
  const float* v = (const float*)d_in[2];
  const float* proj = (const float*)d_in[3];
  float* out = (float*)d_out;
  float* ws = (float*)d_ws;
  // ws layout (floats): [reserved 1024] | kcum 16384 | ctxT f16 (524288 f)
  // => 2.17 MB, identical footprint/offsets to the proven sessions.
  float* ws_kcum = ws + 1024;                  // 16384 floats
  f16*   ws_ctxT = (f16*)(ws + 17408);         // 1,048,576 f16
  // d_out scratch (17.2 MB of 67 MB): written by K2, fully consumed by K2c before
  // K3 overwrites every element of d_out. Every scratch byte written before read.
  float* ctx_part  = out;                      // [64bh][4ns][256m][64e] f32
  float* kcum_part = out + 4194304;            // [64bh][4ns][256m]
  float* stabm     = out + 4259840;            // [64bh][4ns][16tile]
  float* vs_part   = out + 4263936;            // [64bh][4ns][2nsub][64e]
  k2_ctx<<<1024, 512, 0, stream>>>(k, v, proj, ctx_part, kcum_part, stabm, vs_part);
  k2c_red<<<256, 256, 0, stream>>>(ctx_part, kcum_part, stabm, vs_part, ws_kcum, ws_ctxT);
  k3_out<<<1024, 256, 0, stream>>>(q, proj, ws_kcum, ws_ctxT, out);
}

// Round 8
// 387.323 us; speedup vs baseline: 1.4582x; 1.0229x over previous
//
#include <hip/hip_runtime.h>

#define SEQ 4096
#define CDN 0.35355339059327379f   // 64^(-1/4)
#define DIAGC 0.0625f              // 0.5 * CDN^2
#define KEPS 1e-4f

typedef _Float16 f16;
typedef f16 f16x8 __attribute__((ext_vector_type(8)));
typedef f16 f16x4 __attribute__((ext_vector_type(4)));
typedef float f32x4 __attribute__((ext_vector_type(4)));

#define MFMA16(a, b, c) __builtin_amdgcn_mfma_f32_16x16x32_f16(a, b, c, 0, 0, 0)

// ---- proj staged to LDS: 256 rows x stride 72 f16 (b128 reads, conflict-spread) --
#define PSTR 72

__device__ __forceinline__ void stage_proj(const float* __restrict__ proj, f16* plds) {
  int t = threadIdx.x;
  int mrow = t >> 2;
  int cb = (t & 3) * 16;
#pragma unroll
  for (int p = 0; p < 4; ++p) {
    int m = mrow + p * 64;
    const float4* src = (const float4*)(proj + m * 64 + cb);
    f16* dst = plds + m * PSTR + cb;
#pragma unroll
    for (int i = 0; i < 4; ++i) {
      float4 v = src[i];
      f16x4 h = {(f16)v.x, (f16)v.y, (f16)v.z, (f16)v.w};
      *(f16x4*)(dst + i * 4) = h;
    }
  }
}

__device__ __forceinline__ f16x8 proj_frag(const f16* plds, int mtile, int ks, int lane) {
  int m = (lane & 15) + 16 * mtile;
  return *(const f16x8*)(plds + m * PSTR + ks * 32 + (lane >> 4) * 8);
}

// proj fragment direct from f32 global, scaled by CDN (for K2: 2 frags/wave)
__device__ __forceinline__ f16x8 pfrag32s(const float* __restrict__ proj, int mt, int ks, int lane) {
  const float4* p = (const float4*)(proj + (size_t)(16 * mt + (lane & 15)) * 64 + ks * 32 + (lane >> 4) * 8);
  float4 a = p[0], b = p[1];
  f16x8 r = {(f16)(a.x*CDN), (f16)(a.y*CDN), (f16)(a.z*CDN), (f16)(a.w*CDN),
             (f16)(b.x*CDN), (f16)(b.y*CDN), (f16)(b.z*CDN), (f16)(b.w*CDN)};
  return r;
}

// ---------------- K2: m-split x ns-split, ONLINE stab, k+v staged in LDS -----------
// grid = (ns*4 + mc)*64 + bh (bh-minor => 16 blocks of a bh share one XCD L2).
// 1024 blocks x 512 thr. 8 waves: wave w -> m-tile (w&3), n-half (w>>2).
// T14 async-stage: issue raw global loads for tile it+1 at loop top, compute on cur,
// THEN convert+ds_write (HBM latency hides under compute), one barrier per iter.
#define KSTR 72

// full staging (prologue only): k row-major + per-row diag, v transposed
__device__ __forceinline__ void stage_kv(const float* __restrict__ kbh,
                                         const float* __restrict__ vbh,
                                         int n0, f16* ktb, f16* vtb,
                                         float* diagb, int t) {
  int r = t >> 3;
  int c8 = (t & 7) * 8;
  const float4* kp = (const float4*)(kbh + (size_t)(n0 + r) * 64 + c8);
  float4 a = kp[0], b = kp[1];
  float sq = a.x*a.x + a.y*a.y + a.z*a.z + a.w*a.w + b.x*b.x + b.y*b.y + b.z*b.z + b.w*b.w;
  f16x8 h = {(f16)a.x, (f16)a.y, (f16)a.z, (f16)a.w,
             (f16)b.x, (f16)b.y, (f16)b.z, (f16)b.w};
  *(f16x8*)(ktb + r * KSTR + c8) = h;
  sq += __shfl_xor(sq, 1, 64);
  sq += __shfl_xor(sq, 2, 64);
  sq += __shfl_xor(sq, 4, 64);
  if ((t & 7) == 0) diagb[r] = sq * DIAGC;
  int nl = t & 63, e8 = (t >> 6) * 8;
  const float4* vp = (const float4*)(vbh + (size_t)(n0 + nl) * 64 + e8);
  float4 va = vp[0], vb = vp[1];
  vtb[(e8 + 0) * KSTR + nl] = (f16)va.x;
  vtb[(e8 + 1) * KSTR + nl] = (f16)va.y;
  vtb[(e8 + 2) * KSTR + nl] = (f16)va.z;
  vtb[(e8 + 3) * KSTR + nl] = (f16)va.w;
  vtb[(e8 + 4) * KSTR + nl] = (f16)vb.x;
  vtb[(e8 + 5) * KSTR + nl] = (f16)vb.y;
  vtb[(e8 + 6) * KSTR + nl] = (f16)vb.z;
  vtb[(e8 + 7) * KSTR + nl] = (f16)vb.w;
}

__global__ __launch_bounds__(512, 4) void k2_ctx(
    const float* __restrict__ kk, const float* __restrict__ vv,
    const float* __restrict__ proj,
    float* __restrict__ ctx_part, float* __restrict__ kcum_part,
    float* __restrict__ stabm, float* __restrict__ vs_part) {
  __shared__ __align__(16) f16 kt[2][64 * KSTR];   // 18432 B
  __shared__ __align__(16) f16 vt[2][64 * KSTR];   // 18432 B
  __shared__ __align__(16) f16 pht[8][16 * 40];    // 10240 B
  __shared__ float diag_all[2][64];
  __shared__ float red2[4][16];
  __shared__ float stabs[8];
  int bh = blockIdx.x & 63, rest = blockIdx.x >> 6;
  int mc = rest & 3, ns = rest >> 2;               // ns in 0..3
  int t = threadIdx.x;
  int w = t >> 6, lane = t & 63;
  int q4 = lane >> 4, l15 = lane & 15;
  int mtl = w & 3, nsub = w >> 2;
  f16x8 pa0 = pfrag32s(proj, mc * 4 + mtl, 0, lane);   // CDN-scaled proj frags
  f16x8 pa1 = pfrag32s(proj, mc * 4 + mtl, 1, lane);
  const float* kbh = kk + (size_t)bh * SEQ * 64;
  const float* vbh = vv + (size_t)bh * SEQ * 64;
  f32x4 actx[4];
  f32x4 akc = {0.f, 0.f, 0.f, 0.f};
#pragma unroll
  for (int i = 0; i < 4; ++i) actx[i] = (f32x4){0.f, 0.f, 0.f, 0.f};
  float vsacc[4] = {0.f, 0.f, 0.f, 0.f};
  float M = -1e30f;
  f16x8 ones = {(f16)1.f, (f16)1.f, (f16)1.f, (f16)1.f,
                (f16)1.f, (f16)1.f, (f16)1.f, (f16)1.f};
  int nbase = ns * 1024;
  int sr = t >> 3, sc8 = (t & 7) * 8;      // k-staging coords
  int snl = t & 63, se8 = (t >> 6) * 8;    // v-staging coords
  stage_kv(kbh, vbh, nbase, &kt[0][0], &vt[0][0], &diag_all[0][0], t);
  __syncthreads();
#pragma unroll 1
  for (int it = 0; it < 16; ++it) {
    int n0 = nbase + it * 64;
    int cur = it & 1;
    // T14: issue raw loads for it+1 (no conversion/wait yet)
    float4 pka, pkb, pva, pvb;
    if (it < 15) {
      const float4* kp = (const float4*)(kbh + (size_t)(n0 + 64 + sr) * 64 + sc8);
      pka = kp[0]; pkb = kp[1];
      const float4* vp = (const float4*)(vbh + (size_t)(n0 + 64 + snl) * 64 + se8);
      pva = vp[0]; pvb = vp[1];
    }
    const f16* ktc = &kt[cur][0];
    const f16* vcur = &vt[cur][0];
    // k frags for this wave's 32 rows (b128 LDS reads, shared across mtl waves)
    f16x8 ak[2][2];
#pragma unroll
    for (int nt = 0; nt < 2; ++nt) {
      ak[nt][0] = *(const f16x8*)(ktc + (nsub * 32 + nt * 16 + l15) * KSTR + q4 * 8);
      ak[nt][1] = *(const f16x8*)(ktc + (nsub * 32 + nt * 16 + l15) * KSTR + 32 + q4 * 8);
    }
    // dd for both 16-row tiles, then online-max update
    f32x4 accv[2];
#pragma unroll
    for (int nt = 0; nt < 2; ++nt) {
      f32x4 a = {0.f, 0.f, 0.f, 0.f};
      a = MFMA16(ak[nt][0], pa0, a);
      a = MFMA16(ak[nt][1], pa1, a);
      accv[nt] = a;
    }
    float tm = fmaxf(fmaxf(fmaxf(accv[0][0], accv[0][1]), fmaxf(accv[0][2], accv[0][3])),
                     fmaxf(fmaxf(accv[1][0], accv[1][1]), fmaxf(accv[1][2], accv[1][3])));
#pragma unroll
    for (int m = 1; m < 64; m <<= 1) tm = fmaxf(tm, __shfl_xor(tm, m, 64));
    if (tm > M) {  // wave-uniform
      float rs = __expf(M - tm);
      akc *= rs;
#pragma unroll
      for (int et = 0; et < 4; ++et) actx[et] *= rs;
      M = tm;
    }
    // phi = exp(dd - diag - M)  (NO eps; eps handled exactly in K2c)
#pragma unroll
    for (int nt = 0; nt < 2; ++nt) {
      float4 dgv = ((const float4*)&diag_all[cur][0])[nsub * 8 + nt * 4 + q4];
      f16x4 ph;
      ph[0] = (f16)__expf(accv[nt][0] - dgv.x - M);
      ph[1] = (f16)__expf(accv[nt][1] - dgv.y - M);
      ph[2] = (f16)__expf(accv[nt][2] - dgv.z - M);
      ph[3] = (f16)__expf(accv[nt][3] - dgv.w - M);
      *(f16x4*)(&pht[w][l15 * 40 + nt * 16 + q4 * 4]) = ph;
    }
    f16x8 bv[4];
#pragma unroll
    for (int et = 0; et < 4; ++et)
      bv[et] = *(const f16x8*)(vcur + (l15 + 16 * et) * KSTR + nsub * 32 + q4 * 8);
    // v colsum (for the eps*colsum(v) term) - 2 waves only
    if (mc == 0 && mtl == 0) {
#pragma unroll
      for (int et = 0; et < 4; ++et) {
        float s = 0.f;
#pragma unroll
        for (int j = 0; j < 8; ++j) s += (float)bv[et][j];
        vsacc[et] += s;
      }
    }
    f16x8 aph = *(const f16x8*)(&pht[w][l15 * 40 + q4 * 8]);
    akc = MFMA16(aph, ones, akc);
#pragma unroll
    for (int et = 0; et < 4; ++et) actx[et] = MFMA16(aph, bv[et], actx[et]);
    // T14: NOW convert + ds_write the prefetched tile (loads have been in flight
    // across the whole compute phase)
    if (it < 15) {
      f16* ktb = &kt[cur ^ 1][0];
      f16* vtb = &vt[cur ^ 1][0];
      float sq = pka.x*pka.x + pka.y*pka.y + pka.z*pka.z + pka.w*pka.w +
                 pkb.x*pkb.x + pkb.y*pkb.y + pkb.z*pkb.z + pkb.w*pkb.w;
      f16x8 h = {(f16)pka.x, (f16)pka.y, (f16)pka.z, (f16)pka.w,
                 (f16)pkb.x, (f16)pkb.y, (f16)pkb.z, (f16)pkb.w};
      *(f16x8*)(ktb + sr * KSTR + sc8) = h;
      sq += __shfl_xor(sq, 1, 64);
      sq += __shfl_xor(sq, 2, 64);
      sq += __shfl_xor(sq, 4, 64);
      if ((t & 7) == 0) diag_all[cur ^ 1][sr] = sq * DIAGC;
      vtb[(se8 + 0) * KSTR + snl] = (f16)pva.x;
      vtb[(se8 + 1) * KSTR + snl] = (f16)pva.y;
      vtb[(se8 + 2) * KSTR + snl] = (f16)pva.z;
      vtb[(se8 + 3) * KSTR + snl] = (f16)pva.w;
      vtb[(se8 + 4) * KSTR + snl] = (f16)pvb.x;
      vtb[(se8 + 5) * KSTR + snl] = (f16)pvb.y;
      vtb[(se8 + 6) * KSTR + snl] = (f16)pvb.z;
      vtb[(se8 + 7) * KSTR + snl] = (f16)pvb.w;
    }
    __syncthreads();  // next buffers ready; protects cur buffers for next overwrite
  }
  // ---- epilogue: align scales across the nsub pair, reduce, store partials ----
  if (lane == 0) stabs[w] = M;
  __syncthreads();
  float Mp = stabs[w ^ 4];
  float Mt = fmaxf(M, Mp);
  {
    float sc = __expf(M - Mt);
    akc *= sc;
#pragma unroll
    for (int et = 0; et < 4; ++et) actx[et] *= sc;
  }
  if (mc == 0 && mtl == 0) {
#pragma unroll
    for (int et = 0; et < 4; ++et) {
      float s = vsacc[et];
      s += __shfl_xor(s, 16, 64);
      s += __shfl_xor(s, 32, 64);
      if (lane < 16)
        vs_part[(size_t)bh * 512 + (ns * 2 + nsub) * 64 + lane + 16 * et] = s;
    }
  }
  float* red = (float*)&kt[0][0];  // 16 KB needed, 18.4 KB available (kt dead)
  if (nsub == 1) {
#pragma unroll
    for (int et = 0; et < 4; ++et)
#pragma unroll
      for (int r = 0; r < 4; ++r)
        red[mtl * 1024 + (q4 * 4 + r) * 64 + l15 + 16 * et] = actx[et][r];
    if (l15 == 0) {
#pragma unroll
      for (int r = 0; r < 4; ++r) red2[mtl][q4 * 4 + r] = akc[r];
    }
  }
  __syncthreads();
  if (nsub == 0) {
    float* cp = ctx_part + (((size_t)bh * 4 + ns) * 256 + mc * 64 + mtl * 16) * 64;
#pragma unroll
    for (int et = 0; et < 4; ++et)
#pragma unroll
      for (int r = 0; r < 4; ++r)
        cp[(size_t)(q4 * 4 + r) * 64 + l15 + 16 * et] =
            actx[et][r] + red[mtl * 1024 + (q4 * 4 + r) * 64 + l15 + 16 * et];
    if (l15 == 0) {
#pragma unroll
      for (int r = 0; r < 4; ++r)
        kcum_part[((size_t)bh * 4 + ns) * 256 + mc * 64 + mtl * 16 + q4 * 4 + r] =
            akc[r] + red2[mtl][q4 * 4 + r];
    }
    if (lane == 0) stabm[(size_t)bh * 64 + ns * 16 + mc * 4 + mtl] = Mt;
  }
}

// ---------------- K2c: rescale+sum 4 ns-partials -> fp32 kcum + f16 ctxT [e][m] ----
__global__ __launch_bounds__(256) void k2c_red(
    const float* __restrict__ ctx_part, const float* __restrict__ kcum_part,
    const float* __restrict__ stabm, const float* __restrict__ vs_part,
    float* __restrict__ ws_kcum, f16* __restrict__ ws_ctxT) {
  __shared__ float tile[64 * 65];
  __shared__ float sred[64];
  __shared__ float vsum_l[64];
  __shared__ float fac[4][4];  // [ns][tile-in-mq]
  int bh = blockIdx.x & 63, mq = blockIdx.x >> 6;
  int t = threadIdx.x;
  if (t < 64) {
    sred[t] = stabm[(size_t)bh * 64 + t];  // [ns4][tile16]
    float vs = 0.f;
#pragma unroll
    for (int i = 0; i < 8; ++i) vs += vs_part[(size_t)bh * 512 + i * 64 + t];
    vsum_l[t] = vs;
  }
  __syncthreads();
  float S = -1e30f;
#pragma unroll
  for (int i = 0; i < 64; ++i) S = fmaxf(S, sred[i]);
  if (t < 16) fac[t >> 2][t & 3] = __expf(sred[(t >> 2) * 16 + mq * 4 + (t & 3)] - S);
  __syncthreads();
  const float* cp = ctx_part + ((size_t)bh * 4 * 256 + mq * 64) * 64;
#pragma unroll
  for (int i = 0; i < 16; ++i) {
    int idx = t + i * 256;       // over [64m x 64e]
    int ml = idx >> 6, e = idx & 63;
    int tl = ml >> 4;
    float acc = KEPS * vsum_l[e];
#pragma unroll
    for (int ns = 0; ns < 4; ++ns)
      acc += fac[ns][tl] * cp[(size_t)ns * 16384 + idx];
    tile[ml * 65 + e] = acc;
  }
  if (t < 64) {
    int tl = t >> 4;
    float acc = KEPS * 4096.f;
#pragma unroll
    for (int ns = 0; ns < 4; ++ns)
      acc += fac[ns][tl] * kcum_part[((size_t)bh * 4 + ns) * 256 + mq * 64 + t];
    ws_kcum[bh * 256 + mq * 64 + t] = acc;
  }
  __syncthreads();
  f16* ct = ws_ctxT + (size_t)bh * 16384 + mq * 64;
  int mj = t & 63, eg = t >> 6;
#pragma unroll
  for (int i = 0; i < 16; ++i) {
    int e = eg + i * 4;
    ct[(size_t)e * 256 + mj] = (f16)tile[mj * 65 + e];
  }
}

// ---------------- K3: dd_q -> phi_q -> out, two-pass + q-prefetch pipeline ---------
// grid 512 (8 blocks/bh, 512 rows/block, 8 its): halves proj/ctxT re-fetch and
// amortizes the LDS staging prologue. Per it: convert prefetched q -> pass1 (max) ->
// issue q loads for it+1 -> pass2 (recompute+exp) + PV; loads in flight across
// ~700 cycles of MFMA+exp.
#define CSTR 264

__global__ __launch_bounds__(256, 2) void k3_out(
    const float* __restrict__ qq, const float* __restrict__ proj,
    const float* __restrict__ ws_kcum, const f16* __restrict__ ws_ctxT,
    float* __restrict__ out) {
  __shared__ __align__(16) f16 plds[256 * PSTR];   // 36864 B
  __shared__ __align__(16) f16 ctx_l[64 * CSTR];   // 33792 B
  __shared__ __align__(16) f16 phq[4][16 * 72];    // 9216 B, per-wave quarter buffer
  __shared__ __align__(16) float kcl[256];         // 1024 B
  int bh = blockIdx.x >> 3, blk = blockIdx.x & 7;
  int t = threadIdx.x;
  int w = t >> 6, lane = t & 63;
  int q4 = lane >> 4, l15 = lane & 15;
  const float* qbh = qq + (size_t)bh * SEQ * 64;
  int nw0 = blk * 512 + w * 128;  // this wave's first row
  // issue first q tile loads BEFORE staging (latency covered by staging work)
  float4 ca0, cb0, ca1, cb1;
  {
    const float* qr = qbh + (size_t)(nw0 + l15) * 64 + q4 * 8;
    ca0 = ((const float4*)qr)[0];
    cb0 = ((const float4*)qr)[1];
    ca1 = ((const float4*)(qr + 32))[0];
    cb1 = ((const float4*)(qr + 32))[1];
  }
  stage_proj(proj, plds);
  kcl[t] = ws_kcum[bh * 256 + t];
  {
    const f16* cb = ws_ctxT + (size_t)bh * 16384;
#pragma unroll
    for (int i = 0; i < 8; ++i) {
      int c = t + i * 256;
      int e = c >> 5, mo = (c & 31) * 8;
      *(f16x8*)(ctx_l + e * CSTR + mo) = *(const f16x8*)(cb + e * 256 + mo);
    }
  }
  float* obh = out + (size_t)bh * SEQ * 64;
  __syncthreads();
#pragma unroll 1
  for (int it = 0; it < 8; ++it) {
    int n0 = nw0 + it * 16;
    // convert current q tile (regs loaded last iteration / prologue)
    float sq = ca0.x*ca0.x + ca0.y*ca0.y + ca0.z*ca0.z + ca0.w*ca0.w +
               cb0.x*cb0.x + cb0.y*cb0.y + cb0.z*cb0.z + cb0.w*cb0.w +
               ca1.x*ca1.x + ca1.y*ca1.y + ca1.z*ca1.z + ca1.w*ca1.w +
               cb1.x*cb1.x + cb1.y*cb1.y + cb1.z*cb1.z + cb1.w*cb1.w;
    f16x8 bq0 = {(f16)(ca0.x*CDN), (f16)(ca0.y*CDN), (f16)(ca0.z*CDN), (f16)(ca0.w*CDN),
                 (f16)(cb0.x*CDN), (f16)(cb0.y*CDN), (f16)(cb0.z*CDN), (f16)(cb0.w*CDN)};
    f16x8 bq1 = {(f16)(ca1.x*CDN), (f16)(ca1.y*CDN), (f16)(ca1.z*CDN), (f16)(ca1.w*CDN),
                 (f16)(cb1.x*CDN), (f16)(cb1.y*CDN), (f16)(cb1.z*CDN), (f16)(cb1.w*CDN)};
    sq += __shfl_xor(sq, 16, 64);
    sq += __shfl_xor(sq, 32, 64);
    float diag = sq * DIAGC;  // diag for column n = n0 + l15 (ddT orientation)
    // issue q loads for it+1 (in flight across pass1+pass2)
    float4 na0, nb0, na1, nb1;
    if (it < 7) {
      const float* qn = qbh + (size_t)(n0 + 16 + l15) * 64 + q4 * 8;
      na0 = ((const float4*)qn)[0];
      nb0 = ((const float4*)qn)[1];
      na1 = ((const float4*)(qn + 32))[0];
      nb1 = ((const float4*)(qn + 32))[1];
    }
    // pass 1: per-row max only (no dd array kept live)
    float st = -1e30f;
#pragma unroll
    for (int mt = 0; mt < 16; ++mt) {
      f32x4 acc = {0.f, 0.f, 0.f, 0.f};
      acc = MFMA16(proj_frag(plds, mt, 0, lane), bq0, acc);
      acc = MFMA16(proj_frag(plds, mt, 1, lane), bq1, acc);
      st = fmaxf(st, fmaxf(fmaxf(acc[0], acc[1]), fmaxf(acc[2], acc[3])));
    }
    st = fmaxf(st, __shfl_xor(st, 16, 64));
    st = fmaxf(st, __shfl_xor(st, 32, 64));  // per-q-row max
    // pass 2: recompute dd tile-by-tile (bit-identical), exp -> phq -> PV
    float dacc = 0.f;
    f32x4 ao[4];
#pragma unroll
    for (int r = 0; r < 4; ++r) ao[r] = (f32x4){0.f, 0.f, 0.f, 0.f};
#pragma unroll
    for (int qtr = 0; qtr < 4; ++qtr) {
#pragma unroll
      for (int m2 = 0; m2 < 4; ++m2) {
        int mt = qtr * 4 + m2;
        f32x4 acc = {0.f, 0.f, 0.f, 0.f};
        acc = MFMA16(proj_frag(plds, mt, 0, lane), bq0, acc);
        acc = MFMA16(proj_frag(plds, mt, 1, lane), bq1, acc);
        float4 kc = ((const float4*)kcl)[mt * 4 + q4];
        float e0 = __expf(acc[0] - diag - st) + KEPS;
        float e1 = __expf(acc[1] - diag - st) + KEPS;
        float e2 = __expf(acc[2] - diag - st) + KEPS;
        float e3 = __expf(acc[3] - diag - st) + KEPS;
        dacc += e0 * kc.x + e1 * kc.y + e2 * kc.z + e3 * kc.w;
        f16x4 ph;
        ph[0] = (f16)e0; ph[1] = (f16)e1; ph[2] = (f16)e2; ph[3] = (f16)e3;
        *(f16x4*)(&phq[w][l15 * 72 + m2 * 16 + q4 * 4]) = ph;
      }
      // wave-local write->read (lockstep, compiler inserts lgkmcnt)
#pragma unroll
      for (int kl = 0; kl < 2; ++kl) {
        int ks2 = qtr * 2 + kl;
        f16x8 bph = *(const f16x8*)(&phq[w][l15 * 72 + kl * 32 + q4 * 8]);
#pragma unroll
        for (int rte = 0; rte < 4; ++rte) {
          f16x8 act = *(const f16x8*)(ctx_l + (l15 + 16 * rte) * CSTR + ks2 * 32 + q4 * 8);
          ao[rte] = MFMA16(act, bph, ao[rte]);  // outT: row e, col n
        }
      }
    }
    dacc += __shfl_xor(dacc, 16, 64);
    dacc += __shfl_xor(dacc, 32, 64);
    float dinv = 1.0f / dacc;
#pragma unroll
    for (int rte = 0; rte < 4; ++rte) {
      f32x4 o = ao[rte] * dinv;
      __builtin_nontemporal_store(o, (f32x4*)(obh + (size_t)(n0 + l15) * 64 + rte * 16 + q4 * 4));
    }
    if (it < 7) { ca0 = na0; cb0 = nb0; ca1 = na1; cb1 = nb1; }
  }
}

extern "C" void kernel_launch(void* const* d_in, const int* in_sizes, int n_in,
                              void* d_out, int out_size, void* d_ws, size_t ws_size,
                              hipStream_t stream) {
  const float* q = (const float*)d_in[0];
  const float* k = (const float*)d_in[1];
  const float* v = (const float*)d_in[2];
  const float* proj = (const float*)d_in[3];
  float* out = (float*)d_out;
  float* ws = (float*)d_ws;
  // ws layout (floats): [reserved 1024] | kcum 16384 | ctxT f16 (524288 f)
  // => 2.17 MB, identical footprint/offsets to the proven sessions.
  float* ws_kcum = ws + 1024;                  // 16384 floats
  f16*   ws_ctxT = (f16*)(ws + 17408);         // 1,048,576 f16
  // d_out scratch (17.2 MB of 67 MB): written by K2, fully consumed by K2c before
  // K3 overwrites every element of d_out. Every scratch byte written before read.
  float* ctx_part  = out;                      // [64bh][4ns][256m][64e] f32
  float* kcum_part = out + 4194304;            // [64bh][4ns][256m]
  float* stabm     = out + 4259840;            // [64bh][4ns][16tile]
  float* vs_part   = out + 4263936;            // [64bh][4ns][2nsub][64e]
  k2_ctx<<<1024, 512, 0, stream>>>(k, v, proj, ctx_part, kcum_part, stabm, vs_part);
  k2c_red<<<256, 256, 0, stream>>>(ctx_part, kcum_part, stabm, vs_part, ws_kcum, ws_ctxT);
  k3_out<<<512, 256, 0, stream>>>(q, proj, ws_kcum, ws_ctxT, out);
}